// Round 4
// baseline (52635.175 us; speedup 1.0000x reference)
//
#include <hip/hip_runtime.h>
#include <hip/hip_bf16.h>

typedef _Float16 f16;
typedef unsigned short u16;
typedef unsigned char u8;
typedef __attribute__((ext_vector_type(8))) _Float16 f16x8;
typedef __attribute__((ext_vector_type(4))) float f32x4;

#define DI __device__ __forceinline__
#define MFMA16(A, B, C) __builtin_amdgcn_mfma_f32_16x16x32_f16(A, B, C, 0, 0, 0)

constexpr int Bn = 128, Tn = 272, Cn = 96, Hn = 1024, Ln = 256;
constexpr int MELn = 26112, ZDn = 26368;
constexpr int OUT_SM = Bn * Tn * Cn;  // 3342336

DI float sigm(float x) { return 1.f / (1.f + expf(-x)); }
// Clamped narrowing: nothing can become inf/NaN.
DI f16 tof16(float x) { return (f16)fminf(fmaxf(x, -60000.f), 60000.f); }

// 4 fp32 -> 4 f16, 8B store.
DI void cvt4f(float4 v, f16* dst) {
  union { f16 o[4]; uint2 q; } t;
  t.o[0] = tof16(v.x); t.o[1] = tof16(v.y); t.o[2] = tof16(v.z); t.o[3] = tof16(v.w);
  *(uint2*)dst = t.q;
}

// ---- fp8 e4m3fn via bit math (y0 compression fallback for small ws) ----
DI u8 f32_to_e4m3(float x) {
  union { float f; unsigned u; } v; v.f = x;
  unsigned s = (v.u >> 31) << 7;
  float a = fabsf(x);
  if (!(a >= 0.015625f)) {              // subnormal / zero region (a < 2^-6)
    int m = (int)(a * 512.0f + 0.5f);   // ulp = 2^-9
    return (u8)(s | m);
  }
  if (a > 448.f) return (u8)(s | 0x7E);
  v.f = a;
  unsigned e = (v.u >> 23) & 0xFF;
  unsigned mant = (v.u & 0x7FFFFF) + (1u << 19);
  if (mant >> 23) { mant = 0; e += 1; }
  unsigned e8 = e - 120;
  return (u8)(s | (e8 << 3) | (mant >> 20));
}
DI float e4m3_to_f32(u8 b) {
  unsigned s = b >> 7, e = (b >> 3) & 15, m = b & 7;
  float v;
  if (e == 0) v = (float)m * 0.001953125f;
  else { union { unsigned u; float f; } t; t.u = ((e + 120) << 23) | (m << 20); v = t.f; }
  return s ? -v : v;
}

__global__ void melody_fill(const float* __restrict__ mel, f16* __restrict__ zcat) {
  int i = blockIdx.x * 256 + threadIdx.x;
  int b = blockIdx.y;
  if (i < MELn / 4)
    cvt4f(((const float4*)(mel + (size_t)b * MELn))[i],
          zcat + (size_t)b * ZDn + Ln + (size_t)i * 4);
}

__global__ void init_kernel(float* h0, float* h1, float* h2, float* h3,
                            f16* g0, f16* g1, f16* g2, f16* g3,
                            f16* xdec, const float* init_tok) {
  int i = blockIdx.x * 256 + threadIdx.x;
  if (i < Bn * Hn) {
    h0[i] = 0.f; h1[i] = 0.f; h2[i] = 0.f; h3[i] = 0.f;
    g0[i] = (f16)0.f; g1[i] = (f16)0.f; g2[i] = (f16)0.f; g3[i] = (f16)0.f;
  }
  if (i < Bn * Cn) {
    int b = i / Cn, c = i - b * Cn;
    xdec[b * 192 + c] = tof16(init_tok[c]);
  }
}

// One-shot: W16[3H][KWP] = f16(concat(Wih, Whh)) row-major, zero-padded to
// KWP (multiple of 64). Same tof16 as staging -> bit-identical numerics.
__global__ void wconvert(const float* __restrict__ Wih, const float* __restrict__ Whh,
                         int IX, int KWP, f16* __restrict__ W16) {
  const int KW = IX + Hn;
  const int row = blockIdx.x;
  const float* srcI = Wih + (size_t)row * IX;
  const float* srcH = Whh + (size_t)row * Hn;
  f16* dst = W16 + (size_t)row * KWP;
  for (int j = threadIdx.x * 8; j < KWP; j += 256 * 8) {
    union { f16 o[8]; uint4 q; } t;
    if (j < KW) {  // IX%8==0, KW%8==0: chunks never straddle boundaries
      const float* s = (j < IX) ? (srcI + j) : (srcH + (j - IX));
      float4 v0 = *(const float4*)s, v1 = *(const float4*)(s + 4);
      t.o[0] = tof16(v0.x); t.o[1] = tof16(v0.y); t.o[2] = tof16(v0.z); t.o[3] = tof16(v0.w);
      t.o[4] = tof16(v1.x); t.o[5] = tof16(v1.y); t.o[6] = tof16(v1.z); t.o[7] = tof16(v1.w);
    } else {
      t.q = uint4{0, 0, 0, 0};
    }
    *(uint4*)(dst + j) = t.q;
  }
}

struct DirArgs {
  const void* x;      // XM=0: f16, XM=1: fp32, XM=2: fp8
  const float* Wih;   // raw fp32 weights (WM=0 path)
  const float* Whh;
  const f16* W16;     // preconverted concat weights, KWP-padded
  const float* bih;
  const float* bhh;
  const float* hprev_f;
  const f16* hprev_h;
  float* hcur_f;
  f16* hcur_h;
  void* yout;   // layer-0 output base (already offset t*B*2048 + dir*H, in elts)
  int t;
};
struct StepArgs {
  DirArgs d[2];
  const int* length;  // null -> no masking (decoder)
  int xs;             // x row stride in ELEMENTS
};

// ============================================================================
// NEW: M=128 x 32hc x K-slice partial kernel. grid (32 hc, KSP, dirs), 512thr.
// Waves: w = (ki<<2)|mg ; mg covers m-rows [mg*32, mg*32+32) via 2 16-tiles,
// ki covers the 32-K half of each 64-K tile. ki=1 partials folded into ki=0
// via LDS (2 rounds); ki=0 waves store gate partials (R,Z,IN,HN f32) to pbuf.
// Epilogue kernel (same stream) sums KSP slices in fixed order -> determinism.
// ============================================================================
template <int IX, int XM, int YM, int KSP>
__global__ void __launch_bounds__(512) gru_part_kernel(StepArgs a, float* __restrict__ pbuf) {
  constexpr int KW = IX + Hn;
  constexpr int KWP = (KW + 63) & ~63;
  constexpr int NTILES = KWP / 64;
  const DirArgs da = a.d[blockIdx.z];
  const int hc = blockIdx.x * 32;
  const int kz = blockIdx.y;
  const int tb0 = (NTILES * kz) / KSP, tb1 = (NTILES * (kz + 1)) / KSP;
  const int tid = threadIdx.x;
  const int wave = tid >> 6, lane = tid & 63;
  const int ki = wave >> 2, mg = wave & 3;
  const int fr = lane & 15, fq = lane >> 4;

  __shared__ union SMem {
    struct { f16 A[128 * 72]; f16 W[3][32 * 72]; } s;   // 18.4KB + 13.8KB
    float red[8192];                                     // 32KB ki-reduce scratch
  } sm;

  f32x4 acc[4][2][2];  // [gate R,Z,IN,HN][ms][nj] -- all indices compile-time
#pragma unroll
  for (int g = 0; g < 4; ++g)
#pragma unroll
    for (int ms = 0; ms < 2; ++ms)
#pragma unroll
      for (int nj = 0; nj < 2; ++nj) acc[g][ms][nj] = f32x4{0.f, 0.f, 0.f, 0.f};

  // Staging: 1792 16B chunks/tile. c0=tid: A row ra0; c1=tid+512: A row ra0+64;
  // c2=tid+1024: W gate g01 row rr01; c3=tid+1536 (tid<256): W gate2 row rr2.
  const int koq = (tid & 7) * 8;       // 0..56 f16 col within 64-K tile
  const int ra0 = tid >> 3;            // 0..63
  const int g01 = ra0 >> 5;            // 0 or 1
  const int rr01 = ra0 & 31;
  const bool hasW2 = (tid < 256);
  const int rr2 = ra0 & 31;            // == ra0 when hasW2
  const f16* w01 = da.W16 + (size_t)(g01 * Hn + hc + rr01) * KWP + koq;
  const f16* w2p = da.W16 + (size_t)(2 * Hn + hc + rr2) * KWP + koq;
  f16* dW01 = &sm.s.W[g01][0] + rr01 * 72 + koq;
  f16* dW2 = &sm.s.W[2][0] + rr2 * 72 + koq;
  f16* dA0 = sm.s.A + ra0 * 72 + koq;
  f16* dA1 = sm.s.A + (ra0 + 64) * 72 + koq;
  const f16* h0p = da.hprev_h + (size_t)ra0 * Hn;
  const f16* h1p = da.hprev_h + (size_t)(ra0 + 64) * Hn;
  const f16* x0h = (const f16*)da.x + (size_t)ra0 * a.xs;
  const f16* x1h = (const f16*)da.x + (size_t)(ra0 + 64) * a.xs;
  const float* x0f = (const float*)da.x + (size_t)ra0 * a.xs;
  const float* x1f = (const float*)da.x + (size_t)(ra0 + 64) * a.xs;
  const u8* x08 = (const u8*)da.x + (size_t)ra0 * a.xs;
  const u8* x18 = (const u8*)da.x + (size_t)(ra0 + 64) * a.xs;

  // Fragment read offsets (f16 elements) -- proven 16x16x32 per-lane pattern.
  const int aof0 = (mg * 32 + fr) * 72 + ki * 32 + fq * 8;
  const int aof1 = aof0 + 16 * 72;
  const int wofA = fr * 72 + ki * 32 + fq * 8;   // nj=0
  const int wofB = wofA + 16 * 72;               // nj=1

  uint4 rA0{0,0,0,0}, rA1{0,0,0,0}, rW01{0,0,0,0}, rW2{0,0,0,0};
  float4 rxa0, rxb0, rxa1, rxb1;   // XM==1 raw fp32 x
  uint2 r80, r81;                  // XM==2 raw fp8 x

  auto ldtile = [&](int kb) {
    const int kg = kb * 64 + koq;
    if (kg < IX) {
      if (XM == 1) {
        rxa0 = *(const float4*)(x0f + kg); rxb0 = *(const float4*)(x0f + kg + 4);
        rxa1 = *(const float4*)(x1f + kg); rxb1 = *(const float4*)(x1f + kg + 4);
      } else if (XM == 2) {
        r80 = *(const uint2*)(x08 + kg); r81 = *(const uint2*)(x18 + kg);
      } else {
        rA0 = *(const uint4*)(x0h + kg); rA1 = *(const uint4*)(x1h + kg);
      }
    } else if (kg < KW) {
      rA0 = *(const uint4*)(h0p + (kg - IX)); rA1 = *(const uint4*)(h1p + (kg - IX));
    } else {
      rA0 = uint4{0, 0, 0, 0}; rA1 = uint4{0, 0, 0, 0};   // zero-pad tail
    }
    rW01 = *(const uint4*)(w01 + (size_t)kb * 64);
    if (hasW2) rW2 = *(const uint4*)(w2p + (size_t)kb * 64);
  };
  auto sttile = [&](int kb) {
    const int kg = kb * 64 + koq;
    if (XM == 1 && kg < IX) {
      union { f16 o[8]; uint4 q; } t0, t1;
      t0.o[0] = tof16(rxa0.x); t0.o[1] = tof16(rxa0.y);
      t0.o[2] = tof16(rxa0.z); t0.o[3] = tof16(rxa0.w);
      t0.o[4] = tof16(rxb0.x); t0.o[5] = tof16(rxb0.y);
      t0.o[6] = tof16(rxb0.z); t0.o[7] = tof16(rxb0.w);
      t1.o[0] = tof16(rxa1.x); t1.o[1] = tof16(rxa1.y);
      t1.o[2] = tof16(rxa1.z); t1.o[3] = tof16(rxa1.w);
      t1.o[4] = tof16(rxb1.x); t1.o[5] = tof16(rxb1.y);
      t1.o[6] = tof16(rxb1.z); t1.o[7] = tof16(rxb1.w);
      *(uint4*)dA0 = t0.q; *(uint4*)dA1 = t1.q;
    } else if (XM == 2 && kg < IX) {
      union { f16 o[8]; uint4 q; } t0, t1;
#pragma unroll
      for (int j = 0; j < 4; ++j) {
        t0.o[j] = (f16)e4m3_to_f32((u8)(r80.x >> (8 * j)));
        t0.o[4 + j] = (f16)e4m3_to_f32((u8)(r80.y >> (8 * j)));
        t1.o[j] = (f16)e4m3_to_f32((u8)(r81.x >> (8 * j)));
        t1.o[4 + j] = (f16)e4m3_to_f32((u8)(r81.y >> (8 * j)));
      }
      *(uint4*)dA0 = t0.q; *(uint4*)dA1 = t1.q;
    } else {
      *(uint4*)dA0 = rA0; *(uint4*)dA1 = rA1;
    }
    *(uint4*)dW01 = rW01;
    if (hasW2) *(uint4*)dW2 = rW2;
  };

  ldtile(tb0);
#pragma unroll 1
  for (int kb = tb0; kb < tb1; ++kb) {
    sttile(kb);
    __syncthreads();
    if (kb + 1 < tb1) ldtile(kb + 1);   // prefetch under MFMA + barrier
    f16x8 af0 = *(const f16x8*)(sm.s.A + aof0);
    f16x8 af1 = *(const f16x8*)(sm.s.A + aof1);
    f16x8 wra = *(const f16x8*)(&sm.s.W[0][0] + wofA);
    f16x8 wrb = *(const f16x8*)(&sm.s.W[0][0] + wofB);
    f16x8 wza = *(const f16x8*)(&sm.s.W[1][0] + wofA);
    f16x8 wzb = *(const f16x8*)(&sm.s.W[1][0] + wofB);
    f16x8 wna = *(const f16x8*)(&sm.s.W[2][0] + wofA);
    f16x8 wnb = *(const f16x8*)(&sm.s.W[2][0] + wofB);
    acc[0][0][0] = MFMA16(af0, wra, acc[0][0][0]);
    acc[0][0][1] = MFMA16(af0, wrb, acc[0][0][1]);
    acc[0][1][0] = MFMA16(af1, wra, acc[0][1][0]);
    acc[0][1][1] = MFMA16(af1, wrb, acc[0][1][1]);
    acc[1][0][0] = MFMA16(af0, wza, acc[1][0][0]);
    acc[1][0][1] = MFMA16(af0, wzb, acc[1][0][1]);
    acc[1][1][0] = MFMA16(af1, wza, acc[1][1][0]);
    acc[1][1][1] = MFMA16(af1, wzb, acc[1][1][1]);
    const bool isIN = (kb * 64 + ki * 32) < IX;   // block/wave-uniform; 32-aligned
    if (isIN) {
      acc[2][0][0] = MFMA16(af0, wna, acc[2][0][0]);
      acc[2][0][1] = MFMA16(af0, wnb, acc[2][0][1]);
      acc[2][1][0] = MFMA16(af1, wna, acc[2][1][0]);
      acc[2][1][1] = MFMA16(af1, wnb, acc[2][1][1]);
    } else {
      acc[3][0][0] = MFMA16(af0, wna, acc[3][0][0]);
      acc[3][0][1] = MFMA16(af0, wnb, acc[3][0][1]);
      acc[3][1][0] = MFMA16(af1, wna, acc[3][1][0]);
      acc[3][1][1] = MFMA16(af1, wnb, acc[3][1][1]);
    }
    __syncthreads();
  }

  // ki=1 -> ki=0 reduction via LDS scratch (2 gates per round).
#pragma unroll
  for (int rp = 0; rp < 2; ++rp) {
    if (ki == 1) {
#pragma unroll
      for (int gg = 0; gg < 2; ++gg)
#pragma unroll
        for (int ms = 0; ms < 2; ++ms)
#pragma unroll
          for (int nj = 0; nj < 2; ++nj)
            *(f32x4*)(&sm.red[(((gg * 2 + ms) * 2 + nj) * 256 + mg * 64 + lane) * 4]) =
                acc[rp * 2 + gg][ms][nj];
    }
    __syncthreads();
    if (ki == 0) {
#pragma unroll
      for (int gg = 0; gg < 2; ++gg)
#pragma unroll
        for (int ms = 0; ms < 2; ++ms)
#pragma unroll
          for (int nj = 0; nj < 2; ++nj)
            acc[rp * 2 + gg][ms][nj] +=
                *(const f32x4*)(&sm.red[(((gg * 2 + ms) * 2 + nj) * 256 + mg * 64 + lane) * 4]);
    }
    __syncthreads();
  }

  if (ki == 0) {
    float* sl = pbuf + (size_t)((blockIdx.z * 32 + blockIdx.x) * KSP + kz) * 16384;
#pragma unroll
    for (int g = 0; g < 4; ++g)
#pragma unroll
      for (int ms = 0; ms < 2; ++ms)
#pragma unroll
        for (int nj = 0; nj < 2; ++nj)
          *(f32x4*)(sl + (((g * 4 + mg) * 64 + lane) * 16 + (ms * 2 + nj) * 4)) =
              acc[g][ms][nj];
  }
}

// Epilogue: sum KSP slices (fixed order -> deterministic), nonlinearity, masking,
// h + optional y0 stores. grid (32 hc, dirs), 256 thr (4 waves = mg).
template <int YM, int KSP>
__global__ void __launch_bounds__(256) gru_epi_kernel(StepArgs a, const float* __restrict__ pbuf) {
  const DirArgs da = a.d[blockIdx.y];
  const int hc = blockIdx.x * 32;
  const int tid = threadIdx.x;
  const int mg = tid >> 6, lane = tid & 63;
  const int fr = lane & 15, fq = lane >> 4;
  const float* gb = pbuf + (size_t)((blockIdx.y * 32 + blockIdx.x) * KSP) * 16384;
  f32x4 acc[4][2][2];
#pragma unroll
  for (int g = 0; g < 4; ++g)
#pragma unroll
    for (int ms = 0; ms < 2; ++ms)
#pragma unroll
      for (int nj = 0; nj < 2; ++nj) acc[g][ms][nj] = f32x4{0.f, 0.f, 0.f, 0.f};
#pragma unroll
  for (int s = 0; s < KSP; ++s) {
    const float* sl = gb + (size_t)s * 16384;
#pragma unroll
    for (int g = 0; g < 4; ++g)
#pragma unroll
      for (int ms = 0; ms < 2; ++ms)
#pragma unroll
        for (int nj = 0; nj < 2; ++nj)
          acc[g][ms][nj] +=
              *(const f32x4*)(sl + (((g * 4 + mg) * 64 + lane) * 16 + (ms * 2 + nj) * 4));
  }
#pragma unroll
  for (int nj = 0; nj < 2; ++nj) {
    const int k = hc + nj * 16 + fr;
    const float br = da.bih[k] + da.bhh[k];
    const float bz = da.bih[Hn + k] + da.bhh[Hn + k];
    const float bin = da.bih[2 * Hn + k];
    const float bhn = da.bhh[2 * Hn + k];
#pragma unroll
    for (int ms = 0; ms < 2; ++ms)
#pragma unroll
      for (int r = 0; r < 4; ++r) {
        const int b = mg * 32 + ms * 16 + fq * 4 + r;
        const float rg = sigm(acc[0][ms][nj][r] + br);
        const float zg = sigm(acc[1][ms][nj][r] + bz);
        const float ng = tanhf(acc[2][ms][nj][r] + bin + rg * (acc[3][ms][nj][r] + bhn));
        const float hold = da.hprev_f[(size_t)b * Hn + k];
        const bool valid = (a.length == nullptr) || (da.t < a.length[b]);
        const float hnew = valid ? ((1.f - zg) * ng + zg * hold) : hold;
        da.hcur_f[(size_t)b * Hn + k] = hnew;
        da.hcur_h[(size_t)b * Hn + k] = tof16(hnew);
        if (YM == 1)
          ((f16*)da.yout)[(size_t)b * 2048 + k] = valid ? tof16(hnew) : (f16)0.f;
        else if (YM == 2)
          ((u8*)da.yout)[(size_t)b * 2048 + k] = f32_to_e4m3(valid ? hnew : 0.f);
      }
  }
}

// ============================================================================
// r3 fallback kernels (used when ws can't hold W16 / pbuf).
// ============================================================================
template <int IX, int XM, int YM, int WM>
__global__ void __launch_bounds__(WM == 1 ? 512 : 256) gru_step_kernel(StepArgs a) {
  constexpr int KW = IX + Hn;
  constexpr int KWP = (KW + 63) & ~63;
  constexpr int KT = KW / 32;
  constexpr int NT = KWP / 64;
  const DirArgs da = a.d[blockIdx.z];
  const int hc = blockIdx.x * 32;
  const int m0 = blockIdx.y * 32;
  const int tid = threadIdx.x;
  const int wave = tid >> 6, lane = tid & 63;
  const int ki = wave >> 2;
  const int mi = (wave >> 1) & 1, ni = wave & 1;
  const int fr = lane & 15, fq = lane >> 4;

  __shared__ alignas(16) f16 lA[32 * 72];
  __shared__ alignas(16) f16 lW[3][32 * 72];

  f32x4 accR = {0.f, 0.f, 0.f, 0.f};
  f32x4 accZ = accR, accIN = accR, accHN = accR;

  if constexpr (WM == 1) {
    const int idx0 = tid & 255;
    const int r0 = idx0 >> 3;
    const int ko0 = (idx0 & 7) * 8;
    const bool loA = (tid < 256);
    const f16* wb0 = da.W16 + (size_t)(hc + r0) * KWP + ko0;
    const f16* wb1 = da.W16 + (size_t)((loA ? 1 : 2) * Hn + hc + r0) * KWP + ko0;
    f16* d0 = loA ? (lA + r0 * 72 + ko0) : (&lW[0][0] + r0 * 72 + ko0);
    f16* d1 = &lW[loA ? 1 : 2][0] + r0 * 72 + ko0;
    const f16* hrow = da.hprev_h + (size_t)(m0 + r0) * Hn;
    const f16* xrow_h = (const f16*)da.x + (size_t)(m0 + r0) * a.xs;
    const float* xrow_f = (const float*)da.x + (size_t)(m0 + r0) * a.xs;
    const u8* xrow_8 = (const u8*)da.x + (size_t)(m0 + r0) * a.xs;
    const f16* pA = lA + (mi * 16 + fr) * 72 + ki * 32 + fq * 8;
    const f16* pW0 = &lW[0][0] + (ni * 16 + fr) * 72 + ki * 32 + fq * 8;
    const f16* pW1 = &lW[1][0] + (ni * 16 + fr) * 72 + ki * 32 + fq * 8;
    const f16* pW2 = &lW[2][0] + (ni * 16 + fr) * 72 + ki * 32 + fq * 8;

    uint4 rA{0, 0, 0, 0}, r1{0, 0, 0, 0};
    float4 rx0, rx1;
    uint2 r8x;

    auto ldtile = [&](int it) {
      const int kg = it * 64 + ko0;
      if (loA) {
        if (kg < IX) {
          if (XM == 1) {
            rx0 = *(const float4*)(xrow_f + kg);
            rx1 = *(const float4*)(xrow_f + kg + 4);
          } else if (XM == 2) {
            r8x = *(const uint2*)(xrow_8 + kg);
          } else {
            rA = *(const uint4*)(xrow_h + kg);
          }
        } else if (kg < KW) {
          rA = *(const uint4*)(hrow + (kg - IX));
        } else {
          rA = uint4{0, 0, 0, 0};
        }
      } else {
        rA = *(const uint4*)(wb0 + it * 64);
      }
      r1 = *(const uint4*)(wb1 + it * 64);
    };
    auto sttile = [&](int it) {
      const int kg = it * 64 + ko0;
      if (loA && XM == 1 && kg < IX) {
        union { f16 o[8]; uint4 q; } t;
        t.o[0] = tof16(rx0.x); t.o[1] = tof16(rx0.y);
        t.o[2] = tof16(rx0.z); t.o[3] = tof16(rx0.w);
        t.o[4] = tof16(rx1.x); t.o[5] = tof16(rx1.y);
        t.o[6] = tof16(rx1.z); t.o[7] = tof16(rx1.w);
        *(uint4*)d0 = t.q;
      } else if (loA && XM == 2 && kg < IX) {
        union { f16 o[8]; uint4 q; } t;
#pragma unroll
        for (int j = 0; j < 4; ++j) t.o[j] = (f16)e4m3_to_f32((u8)(r8x.x >> (8 * j)));
#pragma unroll
        for (int j = 0; j < 4; ++j) t.o[4 + j] = (f16)e4m3_to_f32((u8)(r8x.y >> (8 * j)));
        *(uint4*)d0 = t.q;
      } else {
        *(uint4*)d0 = rA;
      }
      *(uint4*)d1 = r1;
    };

    ldtile(0);
#pragma unroll 1
    for (int it = 0; it < NT; ++it) {
      sttile(it);
      __syncthreads();
      if (it + 1 < NT) ldtile(it + 1);
      f16x8 af = *(const f16x8*)pA;
      f16x8 wr = *(const f16x8*)pW0;
      f16x8 wz = *(const f16x8*)pW1;
      f16x8 wn = *(const f16x8*)pW2;
      accR = MFMA16(af, wr, accR);
      accZ = MFMA16(af, wz, accZ);
      const int kgw = it * 64 + ki * 32;
      if (kgw < IX) accIN = MFMA16(af, wn, accIN);
      else accHN = MFMA16(af, wn, accHN);
      __syncthreads();
    }
  } else {
#pragma unroll 1
    for (int kb = 0; kb < KT; ++kb) {
      const int k0 = kb * 32;
#pragma unroll
      for (int c = tid; c < 1024; c += 256) {
        const int region = c >> 8;
        const int idx = c & 255;
        const int r = idx >> 3;
        const int ko = (idx & 7) * 4;
        const int kg = k0 + ko;
        if (region == 0) {
          f16* dst = lA + r * 40 + ko;
          if (kg < IX) {
            if (XM == 1) {
              cvt4f(*(const float4*)((const float*)da.x + (size_t)(m0 + r) * a.xs + kg), dst);
            } else if (XM == 2) {
              unsigned r8 = *(const unsigned*)((const u8*)da.x + (size_t)(m0 + r) * a.xs + kg);
              union { f16 o[4]; uint2 q; } t;
#pragma unroll
              for (int j = 0; j < 4; ++j) t.o[j] = (f16)e4m3_to_f32((u8)(r8 >> (8 * j)));
              *(uint2*)dst = t.q;
            } else {
              *(uint2*)dst = *(const uint2*)((const f16*)da.x + (size_t)(m0 + r) * a.xs + kg);
            }
          } else {
            *(uint2*)dst = *(const uint2*)(da.hprev_h + (size_t)(m0 + r) * Hn + (kg - IX));
          }
        } else {
          const int g = region - 1;
          const int row = g * Hn + hc + r;
          const float* src = (kg < IX) ? (da.Wih + (size_t)row * IX + kg)
                                       : (da.Whh + (size_t)row * Hn + (kg - IX));
          cvt4f(*(const float4*)src, &lW[g][0] + r * 40 + ko);
        }
      }
      __syncthreads();
      f16x8 af = *(const f16x8*)(lA + (mi * 16 + fr) * 40 + fq * 8);
      f16x8 wr = *(const f16x8*)(&lW[0][0] + (ni * 16 + fr) * 40 + fq * 8);
      f16x8 wz = *(const f16x8*)(&lW[1][0] + (ni * 16 + fr) * 40 + fq * 8);
      f16x8 wn = *(const f16x8*)(&lW[2][0] + (ni * 16 + fr) * 40 + fq * 8);
      accR = MFMA16(af, wr, accR);
      accZ = MFMA16(af, wz, accZ);
      if (k0 < IX) accIN = MFMA16(af, wn, accIN);
      else accHN = MFMA16(af, wn, accHN);
      __syncthreads();
    }
  }

  if constexpr (WM == 1) {
    __shared__ f32x4 red[4][64][4];
    if (ki == 1) {
      red[wave & 3][lane][0] = accR;
      red[wave & 3][lane][1] = accZ;
      red[wave & 3][lane][2] = accIN;
      red[wave & 3][lane][3] = accHN;
    }
    __syncthreads();
    if (ki == 1) return;
    accR += red[wave & 3][lane][0];
    accZ += red[wave & 3][lane][1];
    accIN += red[wave & 3][lane][2];
    accHN += red[wave & 3][lane][3];
  }

  const int k = hc + ni * 16 + fr;
  const float br = da.bih[k] + da.bhh[k];
  const float bz = da.bih[Hn + k] + da.bhh[Hn + k];
  const float bin = da.bih[2 * Hn + k];
  const float bhn = da.bhh[2 * Hn + k];
#pragma unroll
  for (int r = 0; r < 4; ++r) {
    const int b = m0 + mi * 16 + fq * 4 + r;
    const float rg = sigm(accR[r] + br);
    const float zg = sigm(accZ[r] + bz);
    const float ng = tanhf(accIN[r] + bin + rg * (accHN[r] + bhn));
    const float hold = da.hprev_f[(size_t)b * Hn + k];
    const bool valid = (a.length == nullptr) || (da.t < a.length[b]);
    const float hnew = valid ? ((1.f - zg) * ng + zg * hold) : hold;
    da.hcur_f[(size_t)b * Hn + k] = hnew;
    da.hcur_h[(size_t)b * Hn + k] = tof16(hnew);
    if (YM == 1)
      ((f16*)da.yout)[(size_t)b * 2048 + k] = valid ? tof16(hnew) : (f16)0.f;
    else if (YM == 2)
      ((u8*)da.yout)[(size_t)b * 2048 + k] = f32_to_e4m3(valid ? hnew : 0.f);
  }
}

// Generic NT GEMM: C(128,N) = A(128,K) @ W^T + bias. A is internal f16; W is
// two stacked raw-fp32 blocks [W0 (nsplit rows); W1], converted in staging.
__global__ void __launch_bounds__(256) gemm_nt_kernel(
    const f16* __restrict__ A, const float* __restrict__ W0, const float* __restrict__ W1,
    const float* __restrict__ bias0, const float* __restrict__ bias1, int nsplit,
    float* __restrict__ Cout, int N, int K) {
  const int n0 = blockIdx.x * 64, m0 = blockIdx.y * 32;
  const int tid = threadIdx.x, wave = tid >> 6, lane = tid & 63;
  const int mi = wave >> 1, nj = wave & 1;
  const int fr = lane & 15, fq = lane >> 4;
  __shared__ alignas(16) f16 lA[32 * 40];
  __shared__ alignas(16) f16 lW[64 * 40];
  f32x4 acc0 = {0.f, 0.f, 0.f, 0.f}, acc1 = acc0;
  const int KT = K / 32;
#pragma unroll 1
  for (int kb = 0; kb < KT; ++kb) {
    const int k0 = kb * 32;
#pragma unroll
    for (int c = tid; c < 768; c += 256) {
      if (c < 256) {
        int r = c >> 3, ko = (c & 7) * 4;
        *(uint2*)(lA + r * 40 + ko) =
            *(const uint2*)(A + (size_t)(m0 + r) * K + k0 + ko);
      } else {
        int c2 = c - 256;
        int r = c2 >> 3, ko = (c2 & 7) * 4;
        int n = n0 + r;
        float4 v = {0.f, 0.f, 0.f, 0.f};
        if (n < N) {
          const float* src = (n < nsplit) ? (W0 + (size_t)n * K + k0 + ko)
                                          : (W1 + (size_t)(n - nsplit) * K + k0 + ko);
          v = *(const float4*)src;
        }
        cvt4f(v, lW + r * 40 + ko);
      }
    }
    __syncthreads();
    f16x8 af = *(const f16x8*)(lA + (mi * 16 + fr) * 40 + fq * 8);
    f16x8 w0 = *(const f16x8*)(lW + (nj * 32 + fr) * 40 + fq * 8);
    f16x8 w1 = *(const f16x8*)(lW + (nj * 32 + 16 + fr) * 40 + fq * 8);
    acc0 = MFMA16(af, w0, acc0);
    acc1 = MFMA16(af, w1, acc1);
    __syncthreads();
  }
#pragma unroll
  for (int j = 0; j < 2; ++j) {
    const f32x4 acc = j ? acc1 : acc0;
    const int n = n0 + nj * 32 + j * 16 + fr;
    if (n >= N) continue;
    const float bv = (n < nsplit) ? bias0[n] : bias1[n - nsplit];
#pragma unroll
    for (int r = 0; r < 4; ++r) {
      const int m = m0 + mi * 16 + fq * 4 + r;
      Cout[(size_t)m * N + n] = acc[r] + bv;
    }
  }
}

__global__ void build_hid(const f16* __restrict__ h0f, const f16* __restrict__ h0b,
                          const f16* __restrict__ h1f, const f16* __restrict__ h1b,
                          f16* __restrict__ hidf) {
  int i = blockIdx.x * 256 + threadIdx.x;
  if (i >= Bn * Hn) return;
  int b = i / Hn, k = i - b * Hn;
  f16* row = hidf + (size_t)b * 4096;
  row[k] = h0f[i];
  row[1024 + k] = h0b[i];
  row[2048 + k] = h1f[i];
  row[3072 + k] = h1b[i];
}

__global__ void z_kernel(const float* __restrict__ mulv, const float* __restrict__ eps,
                         f16* __restrict__ zcat, float* __restrict__ out_mu,
                         float* __restrict__ out_lv) {
  int i = blockIdx.x * 256 + threadIdx.x;
  if (i >= Bn * Ln) return;
  int b = i / Ln, j = i - b * Ln;
  float mu = mulv[(size_t)b * 512 + j];
  float lv = mulv[(size_t)b * 512 + 256 + j];
  float z = eps[i] * expf(0.5f * fminf(fmaxf(lv, -80.f), 80.f)) + mu;
  zcat[(size_t)b * ZDn + j] = tof16(z);
  out_mu[i] = mu;
  out_lv[i] = lv;
}

__global__ void zscatter(const float* __restrict__ zres, f16* __restrict__ xdec,
                         float* __restrict__ hdecf, f16* __restrict__ hdech) {
  int i = blockIdx.x * 256 + threadIdx.x;
  if (i >= Bn * 1120) return;
  int b = i / 1120, c = i - b * 1120;
  float v = zres[i];
  if (c < 96) {
    xdec[b * 192 + 96 + c] = tof16(v);
  } else {
    int k = c - 96;
    hdecf[(size_t)b * Hn + k] = v;
    hdech[(size_t)b * Hn + k] = tof16(v);
  }
}

// Logits stored fp32 directly into d_out's softmax region (overwritten
// in-place by softmax_kernel); argmax from fp32 LDS values.
__global__ void __launch_bounds__(256) outproj_kernel(
    const float* __restrict__ hdec, const float* __restrict__ Wout,
    const float* __restrict__ bout, float* __restrict__ logits,
    f16* __restrict__ xdec, int t) {
  const int b = blockIdx.x;
  const int tid = threadIdx.x, wave = tid >> 6, lane = tid & 63;
  __shared__ float hrow[Hn];
  __shared__ float chd[Cn];
  for (int i = tid; i < Hn; i += 256) hrow[i] = hdec[(size_t)b * Hn + i];
  __syncthreads();
  for (int n = wave; n < Cn; n += 4) {
    const float* wr = Wout + (size_t)n * Hn;
    float s = 0.f;
    for (int kk = lane; kk < Hn; kk += 64) s += hrow[kk] * wr[kk];
#pragma unroll
    for (int off = 32; off; off >>= 1) s += __shfl_down(s, off, 64);
    if (lane == 0) chd[n] = s + bout[n];
  }
  __syncthreads();
  float* lrow = logits + ((size_t)b * Tn + t) * Cn;
  for (int c = tid; c < Cn; c += 256) lrow[c] = chd[c];
  if (wave == 0) {
    float va = chd[lane];
    int ia = lane;
    if (lane < 32) {
      float vb = chd[64 + lane];
      if (vb > va) { va = vb; ia = 64 + lane; }
    }
#pragma unroll
    for (int off = 32; off; off >>= 1) {
      float vo = __shfl_down(va, off, 64);
      int io = __shfl_down(ia, off, 64);
      if (vo > va || (vo == va && io < ia)) { va = vo; ia = io; }
    }
    const int amax = __shfl(ia, 0, 64);  // first-occurrence argmax (np semantics)
    xdec[b * 192 + lane] = (f16)((lane == amax) ? 1.f : 0.f);
    if (lane < 32) xdec[b * 192 + 64 + lane] = (f16)((64 + lane == amax) ? 1.f : 0.f);
  }
}

__global__ void softmax_kernel(float* __restrict__ out) {
  const int row = blockIdx.x * 4 + (threadIdx.x >> 6);
  const int lane = threadIdx.x & 63;
  if (row >= Bn * Tn) return;
  float* lr = out + (size_t)row * Cn;    // fp32 logits, overwritten in place
  float v1 = lr[lane];
  float v2 = (lane < 32) ? lr[64 + lane] : -INFINITY;
  float m = fmaxf(v1, v2);
#pragma unroll
  for (int off = 32; off; off >>= 1) m = fmaxf(m, __shfl_xor(m, off, 64));
  float e1 = expf(v1 - m);
  float e2 = (lane < 32) ? expf(v2 - m) : 0.f;
  float s = e1 + e2;
#pragma unroll
  for (int off = 32; off; off >>= 1) s += __shfl_xor(s, off, 64);
  const float inv = 1.f / s, ls = logf(s);
  float* o1 = out + (size_t)OUT_SM + (size_t)row * Cn;
  lr[lane] = e1 * inv;
  o1[lane] = v1 - m - ls;
  if (lane < 32) {
    lr[64 + lane] = e2 * inv;
    o1[64 + lane] = v2 - m - ls;
  }
}

extern "C" void kernel_launch(void* const* d_in, const int* in_sizes, int n_in,
                              void* d_out, int out_size, void* d_ws, size_t ws_size,
                              hipStream_t stream) {
  (void)in_sizes; (void)n_in; (void)out_size;
  char* wsp = (char*)d_ws;
  size_t off = 0;
  auto alloc = [&](size_t bytes) -> void* {
    size_t o = (off + 255) & ~(size_t)255;
    off = o + bytes;
    return (void*)(wsp + o);
  };

  // Tier select on ws_size (constant per session -> graph-safe).
  const bool y16 = (ws_size >= 165000000ull);
  const size_t esz = y16 ? 2 : 1;      // y0 element bytes (f16 vs fp8 e4m3)

  char* y0 = (char*)alloc((size_t)Tn * Bn * 2048 * esz);   // ~136MB or ~68MB
  float* hf[5][2];
  f16* hh[5][2];
  for (int d = 0; d < 5; ++d)
    for (int p = 0; p < 2; ++p) {
      hf[d][p] = (float*)alloc((size_t)Bn * Hn * 4);
      hh[d][p] = (f16*)alloc((size_t)Bn * Hn * 2);
    }
  f16* zcat = (f16*)alloc((size_t)Bn * ZDn * 2);
  float* mulv_f = (float*)alloc((size_t)Bn * 512 * 4);
  float* zres_f = (float*)alloc((size_t)Bn * 1120 * 4);
  f16* hidf = (f16*)alloc((size_t)Bn * 4096 * 2);
  f16* xdec = (f16*)alloc((size_t)Bn * 192 * 2);

  // ---- f16 preconverted-weight cascade, then pbuf (graph-safe: ws_size only).
  f16 *W16_e1f = nullptr, *W16_e1b = nullptr;
  f16 *W16_e0f = nullptr, *W16_e0b = nullptr;
  f16 *W16_dec = nullptr;
  auto try_allocb = [&](size_t bytes) -> void* {
    size_t o = (off + 255) & ~(size_t)255;
    if (o + bytes > ws_size) return nullptr;
    off = o + bytes;
    return (void*)(wsp + o);
  };
  {
    const size_t e1b = (size_t)3 * Hn * 3072 * 2;   // KWP(2048+1024)=3072
    const size_t e0b = (size_t)3 * Hn * 1152 * 2;   // KWP(96+1024)=1152
    const size_t dcb = (size_t)3 * Hn * 1216 * 2;   // KWP(192+1024)=1216
    size_t save = off;
    f16* a1 = (f16*)try_allocb(e1b); f16* b1 = a1 ? (f16*)try_allocb(e1b) : nullptr;
    if (b1) { W16_e1f = a1; W16_e1b = b1; } else off = save;
    save = off;
    f16* a0 = (f16*)try_allocb(e0b); f16* b0 = a0 ? (f16*)try_allocb(e0b) : nullptr;
    if (b0) { W16_e0f = a0; W16_e0b = b0; } else off = save;
    save = off;
    f16* dc = (f16*)try_allocb(dcb);
    if (dc) W16_dec = dc; else off = save;
  }
  // Partial-sum buffer: 256 slices x 16384 f32 = 16MB (covers KSP4 x 64 groups
  // and decoder KSP8 x 32 groups).
  float* pbuf = (float*)try_allocb((size_t)256 * 16384 * 4);

  if (W16_e1f) {
    wconvert<<<dim3(3072), dim3(256), 0, stream>>>(
        (const float*)d_in[11], (const float*)d_in[12], 2048, 3072, W16_e1f);
    wconvert<<<dim3(3072), dim3(256), 0, stream>>>(
        (const float*)d_in[15], (const float*)d_in[16], 2048, 3072, W16_e1b);
  }
  if (W16_e0f) {
    wconvert<<<dim3(3072), dim3(256), 0, stream>>>(
        (const float*)d_in[3], (const float*)d_in[4], Cn, 1152, W16_e0f);
    wconvert<<<dim3(3072), dim3(256), 0, stream>>>(
        (const float*)d_in[7], (const float*)d_in[8], Cn, 1152, W16_e0b);
  }
  if (W16_dec)
    wconvert<<<dim3(3072), dim3(256), 0, stream>>>(
        (const float*)d_in[28], (const float*)d_in[29], 192, 1216, W16_dec);

  init_kernel<<<dim3(512), dim3(256), 0, stream>>>(
      hf[0][0], hf[1][0], hf[2][0], hf[3][0],
      hh[0][0], hh[1][0], hh[2][0], hh[3][0],
      xdec, (const float*)d_in[27]);
  melody_fill<<<dim3((MELn / 4 + 255) / 256, Bn), dim3(256), 0, stream>>>(
      (const float*)d_in[1], zcat);

  const int* lenp = (const int*)d_in[34];

  // ---- encoder layer 0 (bidirectional, fused fwd+bwd per launch) ----
  for (int s = 0; s < Tn; ++s) {
    StepArgs a{};
    const int tf = s, tb = Tn - 1 - s;
    const int p = s & 1, q = (s + 1) & 1;
    a.d[0].x = (const float*)d_in[0] + (size_t)tf * Cn;
    a.d[0].Wih = (const float*)d_in[3]; a.d[0].Whh = (const float*)d_in[4];
    a.d[0].bih = (const float*)d_in[5]; a.d[0].bhh = (const float*)d_in[6];
    a.d[0].W16 = W16_e0f;
    a.d[0].hprev_f = hf[0][p]; a.d[0].hprev_h = hh[0][p];
    a.d[0].hcur_f = hf[0][q]; a.d[0].hcur_h = hh[0][q];
    a.d[0].yout = y0 + (size_t)tf * Bn * 2048 * esz;
    a.d[0].t = tf;
    a.d[1].x = (const float*)d_in[0] + (size_t)tb * Cn;
    a.d[1].Wih = (const float*)d_in[7]; a.d[1].Whh = (const float*)d_in[8];
    a.d[1].bih = (const float*)d_in[9]; a.d[1].bhh = (const float*)d_in[10];
    a.d[1].W16 = W16_e0b;
    a.d[1].hprev_f = hf[1][p]; a.d[1].hprev_h = hh[1][p];
    a.d[1].hcur_f = hf[1][q]; a.d[1].hcur_h = hh[1][q];
    a.d[1].yout = y0 + ((size_t)tb * Bn * 2048 + Hn) * esz;
    a.d[1].t = tb;
    a.length = lenp;
    a.xs = Tn * Cn;   // input_x is (B,T,C): batch stride T*C
    if (W16_e0f && pbuf) {
      if (y16) {
        gru_part_kernel<Cn, 1, 1, 4><<<dim3(32, 4, 2), dim3(512), 0, stream>>>(a, pbuf);
        gru_epi_kernel<1, 4><<<dim3(32, 2), dim3(256), 0, stream>>>(a, pbuf);
      } else {
        gru_part_kernel<Cn, 1, 2, 4><<<dim3(32, 4, 2), dim3(512), 0, stream>>>(a, pbuf);
        gru_epi_kernel<2, 4><<<dim3(32, 2), dim3(256), 0, stream>>>(a, pbuf);
      }
    } else if (y16) {
      if (W16_e0f) gru_step_kernel<Cn, 1, 1, 1><<<dim3(32, 4, 2), dim3(512), 0, stream>>>(a);
      else         gru_step_kernel<Cn, 1, 1, 0><<<dim3(32, 4, 2), dim3(256), 0, stream>>>(a);
    } else {
      if (W16_e0f) gru_step_kernel<Cn, 1, 2, 1><<<dim3(32, 4, 2), dim3(512), 0, stream>>>(a);
      else         gru_step_kernel<Cn, 1, 2, 0><<<dim3(32, 4, 2), dim3(256), 0, stream>>>(a);
    }
  }
  // ---- encoder layer 1 ----
  for (int s = 0; s < Tn; ++s) {
    StepArgs a{};
    const int tf = s, tb = Tn - 1 - s;
    const int p = s & 1, q = (s + 1) & 1;
    a.d[0].x = y0 + (size_t)tf * Bn * 2048 * esz;
    a.d[0].Wih = (const float*)d_in[11]; a.d[0].Whh = (const float*)d_in[12];
    a.d[0].bih = (const float*)d_in[13]; a.d[0].bhh = (const float*)d_in[14];
    a.d[0].W16 = W16_e1f;
    a.d[0].hprev_f = hf[2][p]; a.d[0].hprev_h = hh[2][p];
    a.d[0].hcur_f = hf[2][q]; a.d[0].hcur_h = hh[2][q];
    a.d[0].yout = nullptr;
    a.d[0].t = tf;
    a.d[1].x = y0 + (size_t)tb * Bn * 2048 * esz;
    a.d[1].Wih = (const float*)d_in[15]; a.d[1].Whh = (const float*)d_in[16];
    a.d[1].bih = (const float*)d_in[17]; a.d[1].bhh = (const float*)d_in[18];
    a.d[1].W16 = W16_e1b;
    a.d[1].hprev_f = hf[3][p]; a.d[1].hprev_h = hh[3][p];
    a.d[1].hcur_f = hf[3][q]; a.d[1].hcur_h = hh[3][q];
    a.d[1].yout = nullptr;
    a.d[1].t = tb;
    a.length = lenp;
    a.xs = 2048;
    if (W16_e1f && pbuf) {
      if (y16) {
        gru_part_kernel<2048, 0, 0, 4><<<dim3(32, 4, 2), dim3(512), 0, stream>>>(a, pbuf);
      } else {
        gru_part_kernel<2048, 2, 0, 4><<<dim3(32, 4, 2), dim3(512), 0, stream>>>(a, pbuf);
      }
      gru_epi_kernel<0, 4><<<dim3(32, 2), dim3(256), 0, stream>>>(a, pbuf);
    } else if (y16) {
      if (W16_e1f) gru_step_kernel<2048, 0, 0, 1><<<dim3(32, 4, 2), dim3(512), 0, stream>>>(a);
      else         gru_step_kernel<2048, 0, 0, 0><<<dim3(32, 4, 2), dim3(256), 0, stream>>>(a);
    } else {
      if (W16_e1f) gru_step_kernel<2048, 2, 0, 1><<<dim3(32, 4, 2), dim3(512), 0, stream>>>(a);
      else         gru_step_kernel<2048, 2, 0, 0><<<dim3(32, 4, 2), dim3(256), 0, stream>>>(a);
    }
  }

  // ---- VAE mid-section ----
  build_hid<<<dim3((Bn * Hn + 255) / 256), dim3(256), 0, stream>>>(
      hh[0][0], hh[1][0], hh[2][0], hh[3][0], hidf);
  gemm_nt_kernel<<<dim3(8, 4), dim3(256), 0, stream>>>(
      hidf, (const float*)d_in[19], (const float*)d_in[21],
      (const float*)d_in[20], (const float*)d_in[22], 256, mulv_f, 512, 4096);
  float* outp = (float*)d_out;
  z_kernel<<<dim3((Bn * Ln + 255) / 256), dim3(256), 0, stream>>>(
      mulv_f, (const float*)d_in[2], zcat,
      outp + 2 * (size_t)OUT_SM, outp + 2 * (size_t)OUT_SM + Bn * Ln);
  gemm_nt_kernel<<<dim3(18, 4), dim3(256), 0, stream>>>(
      zcat, (const float*)d_in[23], (const float*)d_in[25],
      (const float*)d_in[24], (const float*)d_in[26], 96, zres_f, 1120, ZDn);
  zscatter<<<dim3((Bn * 1120 + 255) / 256), dim3(256), 0, stream>>>(
      zres_f, xdec, hf[4][0], hh[4][0]);

  // ---- autoregressive decoder ----
  for (int s = 0; s < Tn; ++s) {
    StepArgs a{};
    const int p = s & 1, q = (s + 1) & 1;
    a.d[0].x = xdec;
    a.d[0].Wih = (const float*)d_in[28]; a.d[0].Whh = (const float*)d_in[29];
    a.d[0].bih = (const float*)d_in[30]; a.d[0].bhh = (const float*)d_in[31];
    a.d[0].W16 = W16_dec;
    a.d[0].hprev_f = hf[4][p]; a.d[0].hprev_h = hh[4][p];
    a.d[0].hcur_f = hf[4][q]; a.d[0].hcur_h = hh[4][q];
    a.d[0].yout = nullptr;
    a.d[0].t = s;
    a.d[1] = a.d[0];
    a.length = nullptr;  // decoder: no masking
    a.xs = 192;
    if (W16_dec && pbuf) {
      gru_part_kernel<192, 0, 0, 8><<<dim3(32, 8, 1), dim3(512), 0, stream>>>(a, pbuf);
      gru_epi_kernel<0, 8><<<dim3(32, 1), dim3(256), 0, stream>>>(a, pbuf);
    } else if (W16_dec) {
      gru_step_kernel<192, 0, 0, 1><<<dim3(32, 4, 1), dim3(512), 0, stream>>>(a);
    } else {
      gru_step_kernel<192, 0, 0, 0><<<dim3(32, 4, 1), dim3(256), 0, stream>>>(a);
    }
    outproj_kernel<<<dim3(Bn), dim3(256), 0, stream>>>(
        hf[4][q], (const float*)d_in[32], (const float*)d_in[33],
        outp, xdec, s);
  }

  softmax_kernel<<<dim3((Bn * Tn + 3) / 4), dim3(256), 0, stream>>>(outp);
}

// Round 5
// 48270.941 us; speedup vs baseline: 1.0904x; 1.0904x over previous
//
#include <hip/hip_runtime.h>
#include <hip/hip_bf16.h>

typedef _Float16 f16;
typedef unsigned short u16;
typedef unsigned char u8;
typedef __attribute__((ext_vector_type(8))) _Float16 f16x8;
typedef __attribute__((ext_vector_type(4))) float f32x4;

#define DI __device__ __forceinline__
#define MFMA16(A, B, C) __builtin_amdgcn_mfma_f32_16x16x32_f16(A, B, C, 0, 0, 0)

constexpr int Bn = 128, Tn = 272, Cn = 96, Hn = 1024, Ln = 256;
constexpr int MELn = 26112, ZDn = 26368;
constexpr int OUT_SM = Bn * Tn * Cn;  // 3342336

DI float sigm(float x) { return 1.f / (1.f + expf(-x)); }
// Clamped narrowing: nothing can become inf/NaN.
DI f16 tof16(float x) { return (f16)fminf(fmaxf(x, -60000.f), 60000.f); }

// 4 fp32 -> 4 f16, 8B store.
DI void cvt4f(float4 v, f16* dst) {
  union { f16 o[4]; uint2 q; } t;
  t.o[0] = tof16(v.x); t.o[1] = tof16(v.y); t.o[2] = tof16(v.z); t.o[3] = tof16(v.w);
  *(uint2*)dst = t.q;
}

// ---- fp8 e4m3fn via bit math (y0 compression fallback for small ws) ----
DI u8 f32_to_e4m3(float x) {
  union { float f; unsigned u; } v; v.f = x;
  unsigned s = (v.u >> 31) << 7;
  float a = fabsf(x);
  if (!(a >= 0.015625f)) {              // subnormal / zero region (a < 2^-6)
    int m = (int)(a * 512.0f + 0.5f);   // ulp = 2^-9
    return (u8)(s | m);
  }
  if (a > 448.f) return (u8)(s | 0x7E);
  v.f = a;
  unsigned e = (v.u >> 23) & 0xFF;
  unsigned mant = (v.u & 0x7FFFFF) + (1u << 19);
  if (mant >> 23) { mant = 0; e += 1; }
  unsigned e8 = e - 120;
  return (u8)(s | (e8 << 3) | (mant >> 20));
}
DI float e4m3_to_f32(u8 b) {
  unsigned s = b >> 7, e = (b >> 3) & 15, m = b & 7;
  float v;
  if (e == 0) v = (float)m * 0.001953125f;
  else { union { unsigned u; float f; } t; t.u = ((e + 120) << 23) | (m << 20); v = t.f; }
  return s ? -v : v;
}

__global__ void melody_fill(const float* __restrict__ mel, f16* __restrict__ zcat) {
  int i = blockIdx.x * 256 + threadIdx.x;
  int b = blockIdx.y;
  if (i < MELn / 4)
    cvt4f(((const float4*)(mel + (size_t)b * MELn))[i],
          zcat + (size_t)b * ZDn + Ln + (size_t)i * 4);
}

__global__ void init_kernel(float* h0, float* h1, float* h2, float* h3,
                            f16* g0, f16* g1, f16* g2, f16* g3,
                            f16* xdec, const float* init_tok, unsigned* bars) {
  int i = blockIdx.x * 256 + threadIdx.x;
  if (i < 64) bars[i] = 0u;
  if (i < Bn * Hn) {
    h0[i] = 0.f; h1[i] = 0.f; h2[i] = 0.f; h3[i] = 0.f;
    g0[i] = (f16)0.f; g1[i] = (f16)0.f; g2[i] = (f16)0.f; g3[i] = (f16)0.f;
  }
  if (i < Bn * Cn) {
    int b = i / Cn, c = i - b * Cn;
    xdec[b * 192 + c] = tof16(init_tok[c]);
  }
}

// One-shot: W16[3H][KWP] = f16(concat(Wih, Whh)) row-major, zero-padded to
// KWP (multiple of 64). Same tof16 as staging -> bit-identical numerics.
__global__ void wconvert(const float* __restrict__ Wih, const float* __restrict__ Whh,
                         int IX, int KWP, f16* __restrict__ W16) {
  const int KW = IX + Hn;
  const int row = blockIdx.x;
  const float* srcI = Wih + (size_t)row * IX;
  const float* srcH = Whh + (size_t)row * Hn;
  f16* dst = W16 + (size_t)row * KWP;
  for (int j = threadIdx.x * 8; j < KWP; j += 256 * 8) {
    union { f16 o[8]; uint4 q; } t;
    if (j < KW) {  // IX%8==0, KW%8==0: chunks never straddle boundaries
      const float* s = (j < IX) ? (srcI + j) : (srcH + (j - IX));
      float4 v0 = *(const float4*)s, v1 = *(const float4*)(s + 4);
      t.o[0] = tof16(v0.x); t.o[1] = tof16(v0.y); t.o[2] = tof16(v0.z); t.o[3] = tof16(v0.w);
      t.o[4] = tof16(v1.x); t.o[5] = tof16(v1.y); t.o[6] = tof16(v1.z); t.o[7] = tof16(v1.w);
    } else {
      t.q = uint4{0, 0, 0, 0};
    }
    *(uint4*)(dst + j) = t.q;
  }
}

struct DirArgs {
  const void* x;      // XM=0: f16, XM=1: fp32, XM=2: fp8
  const float* Wih;   // raw fp32 weights (WM=0 path)
  const float* Whh;
  const f16* W16;     // preconverted concat weights, KWP-padded
  const float* bih;
  const float* bhh;
  const float* hprev_f;
  const f16* hprev_h;
  float* hcur_f;
  f16* hcur_h;
  void* yout;   // layer-0 output base (already offset t*B*2048 + dir*H, in elts)
  int t;
};
struct StepArgs {
  DirArgs d[2];
  const int* length;  // null -> no masking (decoder)
  int xs;             // x row stride in ELEMENTS
};

// ---- persistent (whole-layer) sequence kernel args ----
struct SeqDir {
  const void* x;      // XM=0: f16, XM=1: fp32, XM=2: fp8
  const f16* W16;
  const float* bih;
  const float* bhh;
  float* hf0; float* hf1;   // fp32 h ping-pong (start state in hf0)
  f16* hh0; f16* hh1;
  void* y;            // y0 base (dir col-offset pre-applied); null if YM=0
};
struct SeqArgs {
  SeqDir d[2];
  const int* length;
  int xs;             // x row (batch) stride, elements
  int xt;             // x per-t stride, elements
  unsigned* bar;      // monotonic grid-barrier counter (zeroed by init)
};

// ============================================================================
// Persistent bidirectional GRU layer: grid (32 hc, 4 m, 2 dir) = 256 blocks
// x 512 thr = 1 block/CU (co-resident by construction). All T steps run in
// one launch; steps separated by a device-scope software grid barrier
// (monotonic counter -> no reset race; threadfence both sides handles
// per-XCD L2 non-coherence). Inner loop identical to the proven r3 WM1 path.
// ============================================================================
template <int IX, int XM, int YM>
__global__ void __launch_bounds__(512) gru_seq_kernel(SeqArgs a) {
  constexpr int KW = IX + Hn;
  constexpr int KWP = (KW + 63) & ~63;
  constexpr int NT = KWP / 64;
  const int dir = blockIdx.z;
  const SeqDir dd = a.d[dir];
  const int hc = blockIdx.x * 32;
  const int m0 = blockIdx.y * 32;
  const int tid = threadIdx.x;
  const int wave = tid >> 6, lane = tid & 63;
  const int ki = wave >> 2;
  const int mi = (wave >> 1) & 1, ni = wave & 1;
  const int fr = lane & 15, fq = lane >> 4;
  const unsigned nblk = gridDim.x * gridDim.y * gridDim.z;

  __shared__ alignas(16) f16 lA[32 * 72];
  __shared__ alignas(16) f16 lW[3][32 * 72];
  __shared__ f32x4 red[4][64][4];

  // t-invariant staging geometry (identical to r3 WM1)
  const int idx0 = tid & 255;
  const int r0 = idx0 >> 3;
  const int ko0 = (idx0 & 7) * 8;
  const bool loA = (tid < 256);
  const f16* wb0 = dd.W16 + (size_t)(hc + r0) * KWP + ko0;
  const f16* wb1 = dd.W16 + (size_t)((loA ? 1 : 2) * Hn + hc + r0) * KWP + ko0;
  f16* d0 = loA ? (lA + r0 * 72 + ko0) : (&lW[0][0] + r0 * 72 + ko0);
  f16* d1 = &lW[loA ? 1 : 2][0] + r0 * 72 + ko0;
  const f16* pA = lA + (mi * 16 + fr) * 72 + ki * 32 + fq * 8;
  const f16* pW0 = &lW[0][0] + (ni * 16 + fr) * 72 + ki * 32 + fq * 8;
  const f16* pW1 = &lW[1][0] + (ni * 16 + fr) * 72 + ki * 32 + fq * 8;
  const f16* pW2 = &lW[2][0] + (ni * 16 + fr) * 72 + ki * 32 + fq * 8;

  // t-invariant bias scalars
  const int k = hc + ni * 16 + fr;
  const float br = dd.bih[k] + dd.bhh[k];
  const float bz = dd.bih[Hn + k] + dd.bhh[Hn + k];
  const float bin = dd.bih[2 * Hn + k];
  const float bhn = dd.bhh[2 * Hn + k];

  int pp = 0;
  for (int s = 0; s < Tn; ++s) {
    const int t = dir ? (Tn - 1 - s) : s;
    const float* hpf = pp ? dd.hf1 : dd.hf0;
    const f16* hph = pp ? dd.hh1 : dd.hh0;
    float* hcf = pp ? dd.hf0 : dd.hf1;
    f16* hch = pp ? dd.hh0 : dd.hh1;
    const f16* hrow = hph + (size_t)(m0 + r0) * Hn;
    const f16* xrow_h = (const f16*)dd.x + (size_t)(m0 + r0) * a.xs + (size_t)t * a.xt;
    const float* xrow_f = (const float*)dd.x + (size_t)(m0 + r0) * a.xs + (size_t)t * a.xt;
    const u8* xrow_8 = (const u8*)dd.x + (size_t)(m0 + r0) * a.xs + (size_t)t * a.xt;

    f32x4 accR = {0.f, 0.f, 0.f, 0.f};
    f32x4 accZ = accR, accIN = accR, accHN = accR;

    uint4 rA{0, 0, 0, 0}, r1{0, 0, 0, 0};
    float4 rx0, rx1;
    uint2 r8x;

    auto ldtile = [&](int it) {
      const int kg = it * 64 + ko0;
      if (loA) {
        if (kg < IX) {
          if (XM == 1) {
            rx0 = *(const float4*)(xrow_f + kg);
            rx1 = *(const float4*)(xrow_f + kg + 4);
          } else if (XM == 2) {
            r8x = *(const uint2*)(xrow_8 + kg);
          } else {
            rA = *(const uint4*)(xrow_h + kg);
          }
        } else if (kg < KW) {
          rA = *(const uint4*)(hrow + (kg - IX));
        } else {
          rA = uint4{0, 0, 0, 0};
        }
      } else {
        rA = *(const uint4*)(wb0 + it * 64);
      }
      r1 = *(const uint4*)(wb1 + it * 64);
    };
    auto sttile = [&](int it) {
      const int kg = it * 64 + ko0;
      if (loA && XM == 1 && kg < IX) {
        union { f16 o[8]; uint4 q; } t2;
        t2.o[0] = tof16(rx0.x); t2.o[1] = tof16(rx0.y);
        t2.o[2] = tof16(rx0.z); t2.o[3] = tof16(rx0.w);
        t2.o[4] = tof16(rx1.x); t2.o[5] = tof16(rx1.y);
        t2.o[6] = tof16(rx1.z); t2.o[7] = tof16(rx1.w);
        *(uint4*)d0 = t2.q;
      } else if (loA && XM == 2 && kg < IX) {
        union { f16 o[8]; uint4 q; } t2;
#pragma unroll
        for (int j = 0; j < 4; ++j) t2.o[j] = (f16)e4m3_to_f32((u8)(r8x.x >> (8 * j)));
#pragma unroll
        for (int j = 0; j < 4; ++j) t2.o[4 + j] = (f16)e4m3_to_f32((u8)(r8x.y >> (8 * j)));
        *(uint4*)d0 = t2.q;
      } else {
        *(uint4*)d0 = rA;
      }
      *(uint4*)d1 = r1;
    };

    ldtile(0);
#pragma unroll 1
    for (int it = 0; it < NT; ++it) {
      sttile(it);
      __syncthreads();
      if (it + 1 < NT) ldtile(it + 1);   // prefetch under MFMA + barrier
      f16x8 af = *(const f16x8*)pA;
      f16x8 wr = *(const f16x8*)pW0;
      f16x8 wz = *(const f16x8*)pW1;
      f16x8 wn = *(const f16x8*)pW2;
      accR = MFMA16(af, wr, accR);
      accZ = MFMA16(af, wz, accZ);
      const int kgw = it * 64 + ki * 32;
      if (kgw < IX) accIN = MFMA16(af, wn, accIN);
      else accHN = MFMA16(af, wn, accHN);
      __syncthreads();
    }

    // ki=1 -> ki=0 reduction via LDS.
    if (ki == 1) {
      red[wave & 3][lane][0] = accR;
      red[wave & 3][lane][1] = accZ;
      red[wave & 3][lane][2] = accIN;
      red[wave & 3][lane][3] = accHN;
    }
    __syncthreads();
    if (ki == 0) {
      accR += red[wave & 3][lane][0];
      accZ += red[wave & 3][lane][1];
      accIN += red[wave & 3][lane][2];
      accHN += red[wave & 3][lane][3];
#pragma unroll
      for (int r = 0; r < 4; ++r) {
        const int b = m0 + mi * 16 + fq * 4 + r;
        const float rg = sigm(accR[r] + br);
        const float zg = sigm(accZ[r] + bz);
        const float ng = tanhf(accIN[r] + bin + rg * (accHN[r] + bhn));
        const float hold = hpf[(size_t)b * Hn + k];
        const bool valid = (a.length == nullptr) || (t < a.length[b]);
        const float hnew = valid ? ((1.f - zg) * ng + zg * hold) : hold;
        hcf[(size_t)b * Hn + k] = hnew;
        hch[(size_t)b * Hn + k] = tof16(hnew);
        if (YM == 1)
          ((f16*)dd.y)[(size_t)t * Bn * 2048 + (size_t)b * 2048 + k] =
              valid ? tof16(hnew) : (f16)0.f;
        else if (YM == 2)
          ((u8*)dd.y)[(size_t)t * Bn * 2048 + (size_t)b * 2048 + k] =
              f32_to_e4m3(valid ? hnew : 0.f);
      }
    }

    // ---- device-scope grid barrier (monotonic counter; no reset race) ----
    __syncthreads();               // drains this block's stores (vmcnt(0))
    if (tid == 0) {
      __threadfence();             // release: push L2 past XCD boundary
      atomicAdd(a.bar, 1u);
      const unsigned tgt = nblk * (unsigned)(s + 1);
      while (atomicAdd(a.bar, 0u) < tgt) __builtin_amdgcn_s_sleep(2);
      __threadfence();             // acquire: invalidate stale L1/L2
    }
    __syncthreads();
    pp ^= 1;
  }
}

// ============================================================================
// Per-step kernel (r3-proven): decoder + fallbacks.
// ============================================================================
template <int IX, int XM, int YM, int WM>
__global__ void __launch_bounds__(WM == 1 ? 512 : 256) gru_step_kernel(StepArgs a) {
  constexpr int KW = IX + Hn;
  constexpr int KWP = (KW + 63) & ~63;
  constexpr int KT = KW / 32;
  constexpr int NT = KWP / 64;
  const DirArgs da = a.d[blockIdx.z];
  const int hc = blockIdx.x * 32;
  const int m0 = blockIdx.y * 32;
  const int tid = threadIdx.x;
  const int wave = tid >> 6, lane = tid & 63;
  const int ki = wave >> 2;
  const int mi = (wave >> 1) & 1, ni = wave & 1;
  const int fr = lane & 15, fq = lane >> 4;

  __shared__ alignas(16) f16 lA[32 * 72];
  __shared__ alignas(16) f16 lW[3][32 * 72];

  f32x4 accR = {0.f, 0.f, 0.f, 0.f};
  f32x4 accZ = accR, accIN = accR, accHN = accR;

  if constexpr (WM == 1) {
    const int idx0 = tid & 255;
    const int r0 = idx0 >> 3;
    const int ko0 = (idx0 & 7) * 8;
    const bool loA = (tid < 256);
    const f16* wb0 = da.W16 + (size_t)(hc + r0) * KWP + ko0;
    const f16* wb1 = da.W16 + (size_t)((loA ? 1 : 2) * Hn + hc + r0) * KWP + ko0;
    f16* d0 = loA ? (lA + r0 * 72 + ko0) : (&lW[0][0] + r0 * 72 + ko0);
    f16* d1 = &lW[loA ? 1 : 2][0] + r0 * 72 + ko0;
    const f16* hrow = da.hprev_h + (size_t)(m0 + r0) * Hn;
    const f16* xrow_h = (const f16*)da.x + (size_t)(m0 + r0) * a.xs;
    const float* xrow_f = (const float*)da.x + (size_t)(m0 + r0) * a.xs;
    const u8* xrow_8 = (const u8*)da.x + (size_t)(m0 + r0) * a.xs;
    const f16* pA = lA + (mi * 16 + fr) * 72 + ki * 32 + fq * 8;
    const f16* pW0 = &lW[0][0] + (ni * 16 + fr) * 72 + ki * 32 + fq * 8;
    const f16* pW1 = &lW[1][0] + (ni * 16 + fr) * 72 + ki * 32 + fq * 8;
    const f16* pW2 = &lW[2][0] + (ni * 16 + fr) * 72 + ki * 32 + fq * 8;

    uint4 rA{0, 0, 0, 0}, r1{0, 0, 0, 0};
    float4 rx0, rx1;
    uint2 r8x;

    auto ldtile = [&](int it) {
      const int kg = it * 64 + ko0;
      if (loA) {
        if (kg < IX) {
          if (XM == 1) {
            rx0 = *(const float4*)(xrow_f + kg);
            rx1 = *(const float4*)(xrow_f + kg + 4);
          } else if (XM == 2) {
            r8x = *(const uint2*)(xrow_8 + kg);
          } else {
            rA = *(const uint4*)(xrow_h + kg);
          }
        } else if (kg < KW) {
          rA = *(const uint4*)(hrow + (kg - IX));
        } else {
          rA = uint4{0, 0, 0, 0};
        }
      } else {
        rA = *(const uint4*)(wb0 + it * 64);
      }
      r1 = *(const uint4*)(wb1 + it * 64);
    };
    auto sttile = [&](int it) {
      const int kg = it * 64 + ko0;
      if (loA && XM == 1 && kg < IX) {
        union { f16 o[8]; uint4 q; } t;
        t.o[0] = tof16(rx0.x); t.o[1] = tof16(rx0.y);
        t.o[2] = tof16(rx0.z); t.o[3] = tof16(rx0.w);
        t.o[4] = tof16(rx1.x); t.o[5] = tof16(rx1.y);
        t.o[6] = tof16(rx1.z); t.o[7] = tof16(rx1.w);
        *(uint4*)d0 = t.q;
      } else if (loA && XM == 2 && kg < IX) {
        union { f16 o[8]; uint4 q; } t;
#pragma unroll
        for (int j = 0; j < 4; ++j) t.o[j] = (f16)e4m3_to_f32((u8)(r8x.x >> (8 * j)));
#pragma unroll
        for (int j = 0; j < 4; ++j) t.o[4 + j] = (f16)e4m3_to_f32((u8)(r8x.y >> (8 * j)));
        *(uint4*)d0 = t.q;
      } else {
        *(uint4*)d0 = rA;
      }
      *(uint4*)d1 = r1;
    };

    ldtile(0);
#pragma unroll 1
    for (int it = 0; it < NT; ++it) {
      sttile(it);
      __syncthreads();
      if (it + 1 < NT) ldtile(it + 1);
      f16x8 af = *(const f16x8*)pA;
      f16x8 wr = *(const f16x8*)pW0;
      f16x8 wz = *(const f16x8*)pW1;
      f16x8 wn = *(const f16x8*)pW2;
      accR = MFMA16(af, wr, accR);
      accZ = MFMA16(af, wz, accZ);
      const int kgw = it * 64 + ki * 32;
      if (kgw < IX) accIN = MFMA16(af, wn, accIN);
      else accHN = MFMA16(af, wn, accHN);
      __syncthreads();
    }
  } else {
#pragma unroll 1
    for (int kb = 0; kb < KT; ++kb) {
      const int k0 = kb * 32;
#pragma unroll
      for (int c = tid; c < 1024; c += 256) {
        const int region = c >> 8;
        const int idx = c & 255;
        const int r = idx >> 3;
        const int ko = (idx & 7) * 4;
        const int kg = k0 + ko;
        if (region == 0) {
          f16* dst = lA + r * 40 + ko;
          if (kg < IX) {
            if (XM == 1) {
              cvt4f(*(const float4*)((const float*)da.x + (size_t)(m0 + r) * a.xs + kg), dst);
            } else if (XM == 2) {
              unsigned r8 = *(const unsigned*)((const u8*)da.x + (size_t)(m0 + r) * a.xs + kg);
              union { f16 o[4]; uint2 q; } t;
#pragma unroll
              for (int j = 0; j < 4; ++j) t.o[j] = (f16)e4m3_to_f32((u8)(r8 >> (8 * j)));
              *(uint2*)dst = t.q;
            } else {
              *(uint2*)dst = *(const uint2*)((const f16*)da.x + (size_t)(m0 + r) * a.xs + kg);
            }
          } else {
            *(uint2*)dst = *(const uint2*)(da.hprev_h + (size_t)(m0 + r) * Hn + (kg - IX));
          }
        } else {
          const int g = region - 1;
          const int row = g * Hn + hc + r;
          const float* src = (kg < IX) ? (da.Wih + (size_t)row * IX + kg)
                                       : (da.Whh + (size_t)row * Hn + (kg - IX));
          cvt4f(*(const float4*)src, &lW[g][0] + r * 40 + ko);
        }
      }
      __syncthreads();
      f16x8 af = *(const f16x8*)(lA + (mi * 16 + fr) * 40 + fq * 8);
      f16x8 wr = *(const f16x8*)(&lW[0][0] + (ni * 16 + fr) * 40 + fq * 8);
      f16x8 wz = *(const f16x8*)(&lW[1][0] + (ni * 16 + fr) * 40 + fq * 8);
      f16x8 wn = *(const f16x8*)(&lW[2][0] + (ni * 16 + fr) * 40 + fq * 8);
      accR = MFMA16(af, wr, accR);
      accZ = MFMA16(af, wz, accZ);
      if (k0 < IX) accIN = MFMA16(af, wn, accIN);
      else accHN = MFMA16(af, wn, accHN);
      __syncthreads();
    }
  }

  if constexpr (WM == 1) {
    __shared__ f32x4 red[4][64][4];
    if (ki == 1) {
      red[wave & 3][lane][0] = accR;
      red[wave & 3][lane][1] = accZ;
      red[wave & 3][lane][2] = accIN;
      red[wave & 3][lane][3] = accHN;
    }
    __syncthreads();
    if (ki == 1) return;
    accR += red[wave & 3][lane][0];
    accZ += red[wave & 3][lane][1];
    accIN += red[wave & 3][lane][2];
    accHN += red[wave & 3][lane][3];
  }

  const int k = hc + ni * 16 + fr;
  const float br = da.bih[k] + da.bhh[k];
  const float bz = da.bih[Hn + k] + da.bhh[Hn + k];
  const float bin = da.bih[2 * Hn + k];
  const float bhn = da.bhh[2 * Hn + k];
#pragma unroll
  for (int r = 0; r < 4; ++r) {
    const int b = m0 + mi * 16 + fq * 4 + r;
    const float rg = sigm(accR[r] + br);
    const float zg = sigm(accZ[r] + bz);
    const float ng = tanhf(accIN[r] + bin + rg * (accHN[r] + bhn));
    const float hold = da.hprev_f[(size_t)b * Hn + k];
    const bool valid = (a.length == nullptr) || (da.t < a.length[b]);
    const float hnew = valid ? ((1.f - zg) * ng + zg * hold) : hold;
    da.hcur_f[(size_t)b * Hn + k] = hnew;
    da.hcur_h[(size_t)b * Hn + k] = tof16(hnew);
    if (YM == 1)
      ((f16*)da.yout)[(size_t)b * 2048 + k] = valid ? tof16(hnew) : (f16)0.f;
    else if (YM == 2)
      ((u8*)da.yout)[(size_t)b * 2048 + k] = f32_to_e4m3(valid ? hnew : 0.f);
  }
}

// Generic NT GEMM: C(128,N) = A(128,K) @ W^T + bias. A is internal f16; W is
// two stacked raw-fp32 blocks [W0 (nsplit rows); W1], converted in staging.
__global__ void __launch_bounds__(256) gemm_nt_kernel(
    const f16* __restrict__ A, const float* __restrict__ W0, const float* __restrict__ W1,
    const float* __restrict__ bias0, const float* __restrict__ bias1, int nsplit,
    float* __restrict__ Cout, int N, int K) {
  const int n0 = blockIdx.x * 64, m0 = blockIdx.y * 32;
  const int tid = threadIdx.x, wave = tid >> 6, lane = tid & 63;
  const int mi = wave >> 1, nj = wave & 1;
  const int fr = lane & 15, fq = lane >> 4;
  __shared__ alignas(16) f16 lA[32 * 40];
  __shared__ alignas(16) f16 lW[64 * 40];
  f32x4 acc0 = {0.f, 0.f, 0.f, 0.f}, acc1 = acc0;
  const int KT = K / 32;
#pragma unroll 1
  for (int kb = 0; kb < KT; ++kb) {
    const int k0 = kb * 32;
#pragma unroll
    for (int c = tid; c < 768; c += 256) {
      if (c < 256) {
        int r = c >> 3, ko = (c & 7) * 4;
        *(uint2*)(lA + r * 40 + ko) =
            *(const uint2*)(A + (size_t)(m0 + r) * K + k0 + ko);
      } else {
        int c2 = c - 256;
        int r = c2 >> 3, ko = (c2 & 7) * 4;
        int n = n0 + r;
        float4 v = {0.f, 0.f, 0.f, 0.f};
        if (n < N) {
          const float* src = (n < nsplit) ? (W0 + (size_t)n * K + k0 + ko)
                                          : (W1 + (size_t)(n - nsplit) * K + k0 + ko);
          v = *(const float4*)src;
        }
        cvt4f(v, lW + r * 40 + ko);
      }
    }
    __syncthreads();
    f16x8 af = *(const f16x8*)(lA + (mi * 16 + fr) * 40 + fq * 8);
    f16x8 w0 = *(const f16x8*)(lW + (nj * 32 + fr) * 40 + fq * 8);
    f16x8 w1 = *(const f16x8*)(lW + (nj * 32 + 16 + fr) * 40 + fq * 8);
    acc0 = MFMA16(af, w0, acc0);
    acc1 = MFMA16(af, w1, acc1);
    __syncthreads();
  }
#pragma unroll
  for (int j = 0; j < 2; ++j) {
    const f32x4 acc = j ? acc1 : acc0;
    const int n = n0 + nj * 32 + j * 16 + fr;
    if (n >= N) continue;
    const float bv = (n < nsplit) ? bias0[n] : bias1[n - nsplit];
#pragma unroll
    for (int r = 0; r < 4; ++r) {
      const int m = m0 + mi * 16 + fq * 4 + r;
      Cout[(size_t)m * N + n] = acc[r] + bv;
    }
  }
}

__global__ void build_hid(const f16* __restrict__ h0f, const f16* __restrict__ h0b,
                          const f16* __restrict__ h1f, const f16* __restrict__ h1b,
                          f16* __restrict__ hidf) {
  int i = blockIdx.x * 256 + threadIdx.x;
  if (i >= Bn * Hn) return;
  int b = i / Hn, k = i - b * Hn;
  f16* row = hidf + (size_t)b * 4096;
  row[k] = h0f[i];
  row[1024 + k] = h0b[i];
  row[2048 + k] = h1f[i];
  row[3072 + k] = h1b[i];
}

__global__ void z_kernel(const float* __restrict__ mulv, const float* __restrict__ eps,
                         f16* __restrict__ zcat, float* __restrict__ out_mu,
                         float* __restrict__ out_lv) {
  int i = blockIdx.x * 256 + threadIdx.x;
  if (i >= Bn * Ln) return;
  int b = i / Ln, j = i - b * Ln;
  float mu = mulv[(size_t)b * 512 + j];
  float lv = mulv[(size_t)b * 512 + 256 + j];
  float z = eps[i] * expf(0.5f * fminf(fmaxf(lv, -80.f), 80.f)) + mu;
  zcat[(size_t)b * ZDn + j] = tof16(z);
  out_mu[i] = mu;
  out_lv[i] = lv;
}

__global__ void zscatter(const float* __restrict__ zres, f16* __restrict__ xdec,
                         float* __restrict__ hdecf, f16* __restrict__ hdech) {
  int i = blockIdx.x * 256 + threadIdx.x;
  if (i >= Bn * 1120) return;
  int b = i / 1120, c = i - b * 1120;
  float v = zres[i];
  if (c < 96) {
    xdec[b * 192 + 96 + c] = tof16(v);
  } else {
    int k = c - 96;
    hdecf[(size_t)b * Hn + k] = v;
    hdech[(size_t)b * Hn + k] = tof16(v);
  }
}

// Logits stored fp32 directly into d_out's softmax region (overwritten
// in-place by softmax_kernel); argmax from fp32 LDS values.
__global__ void __launch_bounds__(256) outproj_kernel(
    const float* __restrict__ hdec, const float* __restrict__ Wout,
    const float* __restrict__ bout, float* __restrict__ logits,
    f16* __restrict__ xdec, int t) {
  const int b = blockIdx.x;
  const int tid = threadIdx.x, wave = tid >> 6, lane = tid & 63;
  __shared__ float hrow[Hn];
  __shared__ float chd[Cn];
  for (int i = tid; i < Hn; i += 256) hrow[i] = hdec[(size_t)b * Hn + i];
  __syncthreads();
  for (int n = wave; n < Cn; n += 4) {
    const float* wr = Wout + (size_t)n * Hn;
    float s = 0.f;
    for (int kk = lane; kk < Hn; kk += 64) s += hrow[kk] * wr[kk];
#pragma unroll
    for (int off = 32; off; off >>= 1) s += __shfl_down(s, off, 64);
    if (lane == 0) chd[n] = s + bout[n];
  }
  __syncthreads();
  float* lrow = logits + ((size_t)b * Tn + t) * Cn;
  for (int c = tid; c < Cn; c += 256) lrow[c] = chd[c];
  if (wave == 0) {
    float va = chd[lane];
    int ia = lane;
    if (lane < 32) {
      float vb = chd[64 + lane];
      if (vb > va) { va = vb; ia = 64 + lane; }
    }
#pragma unroll
    for (int off = 32; off; off >>= 1) {
      float vo = __shfl_down(va, off, 64);
      int io = __shfl_down(ia, off, 64);
      if (vo > va || (vo == va && io < ia)) { va = vo; ia = io; }
    }
    const int amax = __shfl(ia, 0, 64);  // first-occurrence argmax (np semantics)
    xdec[b * 192 + lane] = (f16)((lane == amax) ? 1.f : 0.f);
    if (lane < 32) xdec[b * 192 + 64 + lane] = (f16)((64 + lane == amax) ? 1.f : 0.f);
  }
}

__global__ void softmax_kernel(float* __restrict__ out) {
  const int row = blockIdx.x * 4 + (threadIdx.x >> 6);
  const int lane = threadIdx.x & 63;
  if (row >= Bn * Tn) return;
  float* lr = out + (size_t)row * Cn;    // fp32 logits, overwritten in place
  float v1 = lr[lane];
  float v2 = (lane < 32) ? lr[64 + lane] : -INFINITY;
  float m = fmaxf(v1, v2);
#pragma unroll
  for (int off = 32; off; off >>= 1) m = fmaxf(m, __shfl_xor(m, off, 64));
  float e1 = expf(v1 - m);
  float e2 = (lane < 32) ? expf(v2 - m) : 0.f;
  float s = e1 + e2;
#pragma unroll
  for (int off = 32; off; off >>= 1) s += __shfl_xor(s, off, 64);
  const float inv = 1.f / s, ls = logf(s);
  float* o1 = out + (size_t)OUT_SM + (size_t)row * Cn;
  lr[lane] = e1 * inv;
  o1[lane] = v1 - m - ls;
  if (lane < 32) {
    lr[64 + lane] = e2 * inv;
    o1[64 + lane] = v2 - m - ls;
  }
}

extern "C" void kernel_launch(void* const* d_in, const int* in_sizes, int n_in,
                              void* d_out, int out_size, void* d_ws, size_t ws_size,
                              hipStream_t stream) {
  (void)in_sizes; (void)n_in; (void)out_size;
  char* wsp = (char*)d_ws;
  size_t off = 0;
  auto alloc = [&](size_t bytes) -> void* {
    size_t o = (off + 255) & ~(size_t)255;
    off = o + bytes;
    return (void*)(wsp + o);
  };

  // Tier select on ws_size (constant per session -> graph-safe).
  const bool y16 = (ws_size >= 165000000ull);
  const size_t esz = y16 ? 2 : 1;      // y0 element bytes (f16 vs fp8 e4m3)

  char* y0 = (char*)alloc((size_t)Tn * Bn * 2048 * esz);   // ~136MB or ~68MB
  float* hf[5][2];
  f16* hh[5][2];
  for (int d = 0; d < 5; ++d)
    for (int p = 0; p < 2; ++p) {
      hf[d][p] = (float*)alloc((size_t)Bn * Hn * 4);
      hh[d][p] = (f16*)alloc((size_t)Bn * Hn * 2);
    }
  f16* zcat = (f16*)alloc((size_t)Bn * ZDn * 2);
  float* mulv_f = (float*)alloc((size_t)Bn * 512 * 4);
  float* zres_f = (float*)alloc((size_t)Bn * 1120 * 4);
  f16* hidf = (f16*)alloc((size_t)Bn * 4096 * 2);
  f16* xdec = (f16*)alloc((size_t)Bn * 192 * 2);
  unsigned* bars = (unsigned*)alloc(256);   // grid-barrier counters (bars[0]=l0, bars[1]=l1)

  // ---- f16 preconverted-weight cascade (graph-safe: ws_size only). ----
  f16 *W16_e1f = nullptr, *W16_e1b = nullptr;
  f16 *W16_e0f = nullptr, *W16_e0b = nullptr;
  f16 *W16_dec = nullptr;
  auto try_allocb = [&](size_t bytes) -> void* {
    size_t o = (off + 255) & ~(size_t)255;
    if (o + bytes > ws_size) return nullptr;
    off = o + bytes;
    return (void*)(wsp + o);
  };
  {
    const size_t e1b = (size_t)3 * Hn * 3072 * 2;   // KWP(2048+1024)=3072
    const size_t e0b = (size_t)3 * Hn * 1152 * 2;   // KWP(96+1024)=1152
    const size_t dcb = (size_t)3 * Hn * 1216 * 2;   // KWP(192+1024)=1216
    size_t save = off;
    f16* a1 = (f16*)try_allocb(e1b); f16* b1 = a1 ? (f16*)try_allocb(e1b) : nullptr;
    if (b1) { W16_e1f = a1; W16_e1b = b1; } else off = save;
    save = off;
    f16* a0 = (f16*)try_allocb(e0b); f16* b0 = a0 ? (f16*)try_allocb(e0b) : nullptr;
    if (b0) { W16_e0f = a0; W16_e0b = b0; } else off = save;
    save = off;
    f16* dc = (f16*)try_allocb(dcb);
    if (dc) W16_dec = dc; else off = save;
  }

  if (W16_e1f) {
    wconvert<<<dim3(3072), dim3(256), 0, stream>>>(
        (const float*)d_in[11], (const float*)d_in[12], 2048, 3072, W16_e1f);
    wconvert<<<dim3(3072), dim3(256), 0, stream>>>(
        (const float*)d_in[15], (const float*)d_in[16], 2048, 3072, W16_e1b);
  }
  if (W16_e0f) {
    wconvert<<<dim3(3072), dim3(256), 0, stream>>>(
        (const float*)d_in[3], (const float*)d_in[4], Cn, 1152, W16_e0f);
    wconvert<<<dim3(3072), dim3(256), 0, stream>>>(
        (const float*)d_in[7], (const float*)d_in[8], Cn, 1152, W16_e0b);
  }
  if (W16_dec)
    wconvert<<<dim3(3072), dim3(256), 0, stream>>>(
        (const float*)d_in[28], (const float*)d_in[29], 192, 1216, W16_dec);

  init_kernel<<<dim3(512), dim3(256), 0, stream>>>(
      hf[0][0], hf[1][0], hf[2][0], hf[3][0],
      hh[0][0], hh[1][0], hh[2][0], hh[3][0],
      xdec, (const float*)d_in[27], bars);
  melody_fill<<<dim3((MELn / 4 + 255) / 256, Bn), dim3(256), 0, stream>>>(
      (const float*)d_in[1], zcat);

  const int* lenp = (const int*)d_in[34];

  // ---- encoder layer 0: persistent kernel (fallback: r3 per-step loop) ----
  if (W16_e0f) {
    SeqArgs sa{};
    sa.d[0] = SeqDir{d_in[0], W16_e0f, (const float*)d_in[5], (const float*)d_in[6],
                     hf[0][0], hf[0][1], hh[0][0], hh[0][1], y0};
    sa.d[1] = SeqDir{d_in[0], W16_e0b, (const float*)d_in[9], (const float*)d_in[10],
                     hf[1][0], hf[1][1], hh[1][0], hh[1][1], y0 + Hn * esz};
    sa.length = lenp;
    sa.xs = Tn * Cn;
    sa.xt = Cn;
    sa.bar = bars + 0;
    if (y16) gru_seq_kernel<Cn, 1, 1><<<dim3(32, 4, 2), dim3(512), 0, stream>>>(sa);
    else     gru_seq_kernel<Cn, 1, 2><<<dim3(32, 4, 2), dim3(512), 0, stream>>>(sa);
  } else {
    for (int s = 0; s < Tn; ++s) {
      StepArgs a{};
      const int tf = s, tb = Tn - 1 - s;
      const int p = s & 1, q = (s + 1) & 1;
      a.d[0].x = (const float*)d_in[0] + (size_t)tf * Cn;
      a.d[0].Wih = (const float*)d_in[3]; a.d[0].Whh = (const float*)d_in[4];
      a.d[0].bih = (const float*)d_in[5]; a.d[0].bhh = (const float*)d_in[6];
      a.d[0].hprev_f = hf[0][p]; a.d[0].hprev_h = hh[0][p];
      a.d[0].hcur_f = hf[0][q]; a.d[0].hcur_h = hh[0][q];
      a.d[0].yout = y0 + (size_t)tf * Bn * 2048 * esz;
      a.d[0].t = tf;
      a.d[1].x = (const float*)d_in[0] + (size_t)tb * Cn;
      a.d[1].Wih = (const float*)d_in[7]; a.d[1].Whh = (const float*)d_in[8];
      a.d[1].bih = (const float*)d_in[9]; a.d[1].bhh = (const float*)d_in[10];
      a.d[1].hprev_f = hf[1][p]; a.d[1].hprev_h = hh[1][p];
      a.d[1].hcur_f = hf[1][q]; a.d[1].hcur_h = hh[1][q];
      a.d[1].yout = y0 + ((size_t)tb * Bn * 2048 + Hn) * esz;
      a.d[1].t = tb;
      a.length = lenp;
      a.xs = Tn * Cn;
      if (y16) gru_step_kernel<Cn, 1, 1, 0><<<dim3(32, 4, 2), dim3(256), 0, stream>>>(a);
      else     gru_step_kernel<Cn, 1, 2, 0><<<dim3(32, 4, 2), dim3(256), 0, stream>>>(a);
    }
  }

  // ---- encoder layer 1: persistent kernel (fallback: r3 per-step loop) ----
  if (W16_e1f) {
    SeqArgs sa{};
    sa.d[0] = SeqDir{y0, W16_e1f, (const float*)d_in[13], (const float*)d_in[14],
                     hf[2][0], hf[2][1], hh[2][0], hh[2][1], nullptr};
    sa.d[1] = SeqDir{y0, W16_e1b, (const float*)d_in[17], (const float*)d_in[18],
                     hf[3][0], hf[3][1], hh[3][0], hh[3][1], nullptr};
    sa.length = lenp;
    sa.xs = 2048;
    sa.xt = Bn * 2048;
    sa.bar = bars + 16;
    if (y16) gru_seq_kernel<2048, 0, 0><<<dim3(32, 4, 2), dim3(512), 0, stream>>>(sa);
    else     gru_seq_kernel<2048, 2, 0><<<dim3(32, 4, 2), dim3(512), 0, stream>>>(sa);
  } else {
    for (int s = 0; s < Tn; ++s) {
      StepArgs a{};
      const int tf = s, tb = Tn - 1 - s;
      const int p = s & 1, q = (s + 1) & 1;
      a.d[0].x = y0 + (size_t)tf * Bn * 2048 * esz;
      a.d[0].Wih = (const float*)d_in[11]; a.d[0].Whh = (const float*)d_in[12];
      a.d[0].bih = (const float*)d_in[13]; a.d[0].bhh = (const float*)d_in[14];
      a.d[0].hprev_f = hf[2][p]; a.d[0].hprev_h = hh[2][p];
      a.d[0].hcur_f = hf[2][q]; a.d[0].hcur_h = hh[2][q];
      a.d[0].yout = nullptr;
      a.d[0].t = tf;
      a.d[1].x = y0 + (size_t)tb * Bn * 2048 * esz;
      a.d[1].Wih = (const float*)d_in[15]; a.d[1].Whh = (const float*)d_in[16];
      a.d[1].bih = (const float*)d_in[17]; a.d[1].bhh = (const float*)d_in[18];
      a.d[1].hprev_f = hf[3][p]; a.d[1].hprev_h = hh[3][p];
      a.d[1].hcur_f = hf[3][q]; a.d[1].hcur_h = hh[3][q];
      a.d[1].yout = nullptr;
      a.d[1].t = tb;
      a.length = lenp;
      a.xs = 2048;
      if (y16) gru_step_kernel<2048, 0, 0, 0><<<dim3(32, 4, 2), dim3(256), 0, stream>>>(a);
      else     gru_step_kernel<2048, 2, 0, 0><<<dim3(32, 4, 2), dim3(256), 0, stream>>>(a);
    }
  }

  // ---- VAE mid-section ----
  build_hid<<<dim3((Bn * Hn + 255) / 256), dim3(256), 0, stream>>>(
      hh[0][0], hh[1][0], hh[2][0], hh[3][0], hidf);
  gemm_nt_kernel<<<dim3(8, 4), dim3(256), 0, stream>>>(
      hidf, (const float*)d_in[19], (const float*)d_in[21],
      (const float*)d_in[20], (const float*)d_in[22], 256, mulv_f, 512, 4096);
  float* outp = (float*)d_out;
  z_kernel<<<dim3((Bn * Ln + 255) / 256), dim3(256), 0, stream>>>(
      mulv_f, (const float*)d_in[2], zcat,
      outp + 2 * (size_t)OUT_SM, outp + 2 * (size_t)OUT_SM + Bn * Ln);
  gemm_nt_kernel<<<dim3(18, 4), dim3(256), 0, stream>>>(
      zcat, (const float*)d_in[23], (const float*)d_in[25],
      (const float*)d_in[24], (const float*)d_in[26], 96, zres_f, 1120, ZDn);
  zscatter<<<dim3((Bn * 1120 + 255) / 256), dim3(256), 0, stream>>>(
      zres_f, xdec, hf[4][0], hh[4][0]);

  // ---- autoregressive decoder (r3-proven per-step path) ----
  for (int s = 0; s < Tn; ++s) {
    StepArgs a{};
    const int p = s & 1, q = (s + 1) & 1;
    a.d[0].x = xdec;
    a.d[0].Wih = (const float*)d_in[28]; a.d[0].Whh = (const float*)d_in[29];
    a.d[0].bih = (const float*)d_in[30]; a.d[0].bhh = (const float*)d_in[31];
    a.d[0].W16 = W16_dec;
    a.d[0].hprev_f = hf[4][p]; a.d[0].hprev_h = hh[4][p];
    a.d[0].hcur_f = hf[4][q]; a.d[0].hcur_h = hh[4][q];
    a.d[0].yout = nullptr;
    a.d[0].t = s;
    a.d[1] = a.d[0];
    a.length = nullptr;  // decoder: no masking
    a.xs = 192;
    if (W16_dec) gru_step_kernel<192, 0, 0, 1><<<dim3(32, 4, 1), dim3(512), 0, stream>>>(a);
    else         gru_step_kernel<192, 0, 0, 0><<<dim3(32, 4, 1), dim3(256), 0, stream>>>(a);
    outproj_kernel<<<dim3(Bn), dim3(256), 0, stream>>>(
        hf[4][q], (const float*)d_in[32], (const float*)d_in[33],
        outp, xdec, s);
  }

  softmax_kernel<<<dim3((Bn * Tn + 3) / 4), dim3(256), 0, stream>>>(outp);
}

// Round 6
// 36329.791 us; speedup vs baseline: 1.4488x; 1.3287x over previous
//
#include <hip/hip_runtime.h>
#include <hip/hip_bf16.h>

typedef _Float16 f16;
typedef unsigned short u16;
typedef unsigned char u8;
typedef __attribute__((ext_vector_type(8))) _Float16 f16x8;
typedef __attribute__((ext_vector_type(4))) float f32x4;

#define DI __device__ __forceinline__
#define MFMA16(A, B, C) __builtin_amdgcn_mfma_f32_16x16x32_f16(A, B, C, 0, 0, 0)

constexpr int Bn = 128, Tn = 272, Cn = 96, Hn = 1024, Ln = 256;
constexpr int MELn = 26112, ZDn = 26368;
constexpr int OUT_SM = Bn * Tn * Cn;  // 3342336

DI float sigm(float x) { return 1.f / (1.f + expf(-x)); }
// Clamped narrowing: nothing can become inf/NaN.
DI f16 tof16(float x) { return (f16)fminf(fmaxf(x, -60000.f), 60000.f); }

// 4 fp32 -> 4 f16, 8B store.
DI void cvt4f(float4 v, f16* dst) {
  union { f16 o[4]; uint2 q; } t;
  t.o[0] = tof16(v.x); t.o[1] = tof16(v.y); t.o[2] = tof16(v.z); t.o[3] = tof16(v.w);
  *(uint2*)dst = t.q;
}

// ---- fp8 e4m3fn via bit math (y0 compression fallback for small ws) ----
DI u8 f32_to_e4m3(float x) {
  union { float f; unsigned u; } v; v.f = x;
  unsigned s = (v.u >> 31) << 7;
  float a = fabsf(x);
  if (!(a >= 0.015625f)) {              // subnormal / zero region (a < 2^-6)
    int m = (int)(a * 512.0f + 0.5f);   // ulp = 2^-9
    return (u8)(s | m);
  }
  if (a > 448.f) return (u8)(s | 0x7E);
  v.f = a;
  unsigned e = (v.u >> 23) & 0xFF;
  unsigned mant = (v.u & 0x7FFFFF) + (1u << 19);
  if (mant >> 23) { mant = 0; e += 1; }
  unsigned e8 = e - 120;
  return (u8)(s | (e8 << 3) | (mant >> 20));
}
DI float e4m3_to_f32(u8 b) {
  unsigned s = b >> 7, e = (b >> 3) & 15, m = b & 7;
  float v;
  if (e == 0) v = (float)m * 0.001953125f;
  else { union { unsigned u; float f; } t; t.u = ((e + 120) << 23) | (m << 20); v = t.f; }
  return s ? -v : v;
}

__global__ void melody_fill(const float* __restrict__ mel, f16* __restrict__ zcat) {
  int i = blockIdx.x * 256 + threadIdx.x;
  int b = blockIdx.y;
  if (i < MELn / 4)
    cvt4f(((const float4*)(mel + (size_t)b * MELn))[i],
          zcat + (size_t)b * ZDn + Ln + (size_t)i * 4);
}

__global__ void init_kernel(float* h0, float* h1, float* h2, float* h3,
                            f16* g0, f16* g1, f16* g2, f16* g3,
                            f16* xdec, const float* init_tok) {
  int i = blockIdx.x * 256 + threadIdx.x;
  if (i < Bn * Hn) {
    h0[i] = 0.f; h1[i] = 0.f; h2[i] = 0.f; h3[i] = 0.f;
    g0[i] = (f16)0.f; g1[i] = (f16)0.f; g2[i] = (f16)0.f; g3[i] = (f16)0.f;
  }
  if (i < Bn * Cn) {
    int b = i / Cn, c = i - b * Cn;
    xdec[b * 192 + c] = tof16(init_tok[c]);
  }
}

// One-shot: W16[3H][KWP] = f16(concat(Wih, Whh)) row-major, zero-padded to
// KWP (multiple of 64). Same tof16 as staging -> bit-identical numerics.
__global__ void wconvert(const float* __restrict__ Wih, const float* __restrict__ Whh,
                         int IX, int KWP, f16* __restrict__ W16) {
  const int KW = IX + Hn;
  const int row = blockIdx.x;
  const float* srcI = Wih + (size_t)row * IX;
  const float* srcH = Whh + (size_t)row * Hn;
  f16* dst = W16 + (size_t)row * KWP;
  for (int j = threadIdx.x * 8; j < KWP; j += 256 * 8) {
    union { f16 o[8]; uint4 q; } t;
    if (j < KW) {  // IX%8==0, KW%8==0: chunks never straddle boundaries
      const float* s = (j < IX) ? (srcI + j) : (srcH + (j - IX));
      float4 v0 = *(const float4*)s, v1 = *(const float4*)(s + 4);
      t.o[0] = tof16(v0.x); t.o[1] = tof16(v0.y); t.o[2] = tof16(v0.z); t.o[3] = tof16(v0.w);
      t.o[4] = tof16(v1.x); t.o[5] = tof16(v1.y); t.o[6] = tof16(v1.z); t.o[7] = tof16(v1.w);
    } else {
      t.q = uint4{0, 0, 0, 0};
    }
    *(uint4*)(dst + j) = t.q;
  }
}

struct DirArgs {
  const void* x;      // XM=0: f16, XM=1: fp32, XM=2: fp8
  const float* Wih;   // raw fp32 weights (WM=0 path)
  const float* Whh;
  const f16* W16;     // preconverted concat weights, KWP-padded
  const float* bih;
  const float* bhh;
  const float* hprev_f;
  const f16* hprev_h;
  float* hcur_f;
  f16* hcur_h;
  void* yout;   // layer-0 output base (already offset t*B*2048 + dir*H, in elts)
  int t;
};
struct StepArgs {
  DirArgs d[2];
  const int* length;  // null -> no masking (decoder)
  int xs;             // x row stride in ELEMENTS
};

// Fused GRU step (r3-proven structure). 32 batch x 32 h-cols per block.
// XM: x dtype (0=f16,1=fp32,2=fp8). YM: y0 store (0=none,1=f16,2=fp8).
// WM=0: legacy fp32-weight staging, 256 thr / 4 waves, 32-K steps, 2 barriers.
// WM=1: preconverted f16 weights, 512 thr / 8 waves, 64-K steps, K-half split
//       across wave pairs (ki), AND double-buffered LDS: stage tile it+1 into
//       buf^1 while MFMA consumes buf -> ONE barrier per tile (r3 had two).
template <int IX, int XM, int YM, int WM>
__global__ void __launch_bounds__(WM == 1 ? 512 : 256) gru_step_kernel(StepArgs a) {
  constexpr int KW = IX + Hn;
  constexpr int KWP = (KW + 63) & ~63;
  constexpr int KT = KW / 32;          // legacy 32-K step count (KW%32==0)
  constexpr int NT = KWP / 64;         // WM1 64-K step count
  const DirArgs da = a.d[blockIdx.z];
  const int hc = blockIdx.x * 32;
  const int m0 = blockIdx.y * 32;
  const int tid = threadIdx.x;
  const int wave = tid >> 6, lane = tid & 63;
  const int ki = wave >> 2;
  const int mi = (wave >> 1) & 1, ni = wave & 1;
  const int fr = lane & 15, fq = lane >> 4;

  // Double-buffered (WM1). Legacy WM0 uses buffer 0 with 40-stride only.
  __shared__ alignas(16) f16 lA[2][32 * 72];
  __shared__ alignas(16) f16 lW[2][3][32 * 72];

  f32x4 accR = {0.f, 0.f, 0.f, 0.f};
  f32x4 accZ = accR, accIN = accR, accHN = accR;

  if constexpr (WM == 1) {
    const int idx0 = tid & 255;
    const int r0 = idx0 >> 3;            // 0..31 row
    const int ko0 = (idx0 & 7) * 8;      // 0..56 f16 col within 64-K tile
    const bool loA = (tid < 256);
    const f16* wb0 = da.W16 + (size_t)(hc + r0) * KWP + ko0;                    // gate0 (!loA)
    const f16* wb1 = da.W16 + (size_t)((loA ? 1 : 2) * Hn + hc + r0) * KWP + ko0;
    // staging dsts, both buffers
    f16* d0_0 = loA ? (&lA[0][0] + r0 * 72 + ko0) : (&lW[0][0][0] + r0 * 72 + ko0);
    f16* d0_1 = loA ? (&lA[1][0] + r0 * 72 + ko0) : (&lW[1][0][0] + r0 * 72 + ko0);
    f16* d1_0 = &lW[0][loA ? 1 : 2][0] + r0 * 72 + ko0;
    f16* d1_1 = &lW[1][loA ? 1 : 2][0] + r0 * 72 + ko0;
    const f16* hrow = da.hprev_h + (size_t)(m0 + r0) * Hn;
    const f16* xrow_h = (const f16*)da.x + (size_t)(m0 + r0) * a.xs;
    const float* xrow_f = (const float*)da.x + (size_t)(m0 + r0) * a.xs;
    const u8* xrow_8 = (const u8*)da.x + (size_t)(m0 + r0) * a.xs;
    // fragment ptrs, both buffers
    const int fofA = (mi * 16 + fr) * 72 + ki * 32 + fq * 8;
    const int fofW = (ni * 16 + fr) * 72 + ki * 32 + fq * 8;
    const f16* pA0 = &lA[0][0] + fofA;   const f16* pA1 = &lA[1][0] + fofA;
    const f16* pW00 = &lW[0][0][0] + fofW; const f16* pW01 = &lW[1][0][0] + fofW;
    const f16* pW10 = &lW[0][1][0] + fofW; const f16* pW11 = &lW[1][1][0] + fofW;
    const f16* pW20 = &lW[0][2][0] + fofW; const f16* pW21 = &lW[1][2][0] + fofW;

    uint4 rA{0, 0, 0, 0}, r1{0, 0, 0, 0};
    float4 rx0, rx1;   // XM==1 x-part raw
    uint2 r8x;         // XM==2 x-part raw

    auto ldtile = [&](int it) {
      const int kg = it * 64 + ko0;
      if (loA) {
        if (kg < IX) {
          if (XM == 1) {
            rx0 = *(const float4*)(xrow_f + kg);
            rx1 = *(const float4*)(xrow_f + kg + 4);
          } else if (XM == 2) {
            r8x = *(const uint2*)(xrow_8 + kg);
          } else {
            rA = *(const uint4*)(xrow_h + kg);
          }
        } else if (kg < KW) {
          rA = *(const uint4*)(hrow + (kg - IX));
        } else {
          rA = uint4{0, 0, 0, 0};        // zero-pad tail
        }
      } else {
        rA = *(const uint4*)(wb0 + it * 64);
      }
      r1 = *(const uint4*)(wb1 + it * 64);
    };
    auto sttile = [&](int it, bool buf1) {
      f16* d0 = buf1 ? d0_1 : d0_0;
      f16* d1 = buf1 ? d1_1 : d1_0;
      const int kg = it * 64 + ko0;
      if (loA && XM == 1 && kg < IX) {
        union { f16 o[8]; uint4 q; } t;
        t.o[0] = tof16(rx0.x); t.o[1] = tof16(rx0.y);
        t.o[2] = tof16(rx0.z); t.o[3] = tof16(rx0.w);
        t.o[4] = tof16(rx1.x); t.o[5] = tof16(rx1.y);
        t.o[6] = tof16(rx1.z); t.o[7] = tof16(rx1.w);
        *(uint4*)d0 = t.q;
      } else if (loA && XM == 2 && kg < IX) {
        union { f16 o[8]; uint4 q; } t;
#pragma unroll
        for (int j = 0; j < 4; ++j) t.o[j] = (f16)e4m3_to_f32((u8)(r8x.x >> (8 * j)));
#pragma unroll
        for (int j = 0; j < 4; ++j) t.o[4 + j] = (f16)e4m3_to_f32((u8)(r8x.y >> (8 * j)));
        *(uint4*)d0 = t.q;
      } else {
        *(uint4*)d0 = rA;
      }
      *(uint4*)d1 = r1;
    };

    // prologue: tile 0 into buf0
    ldtile(0);
    sttile(0, false);
    __syncthreads();
#pragma unroll 1
    for (int it = 0; it < NT; ++it) {
      const bool odd = it & 1;
      if (it + 1 < NT) ldtile(it + 1);        // global loads overlap MFMA below
      f16x8 af = *(const f16x8*)(odd ? pA1 : pA0);
      f16x8 wr = *(const f16x8*)(odd ? pW01 : pW00);
      f16x8 wz = *(const f16x8*)(odd ? pW11 : pW10);
      f16x8 wn = *(const f16x8*)(odd ? pW21 : pW20);
      accR = MFMA16(af, wr, accR);
      accZ = MFMA16(af, wz, accZ);
      const int kgw = it * 64 + ki * 32;      // wave-uniform
      if (kgw < IX) accIN = MFMA16(af, wn, accIN);
      else accHN = MFMA16(af, wn, accHN);
      if (it + 1 < NT) sttile(it + 1, !odd);  // write OTHER buffer: no hazard
      __syncthreads();                        // single barrier per tile
    }
  } else {
    // ---- legacy fp32-weight staging path (256 threads, buffer 0) ----
#pragma unroll 1
    for (int kb = 0; kb < KT; ++kb) {
      const int k0 = kb * 32;
#pragma unroll
      for (int c = tid; c < 1024; c += 256) {
        const int region = c >> 8;
        const int idx = c & 255;
        const int r = idx >> 3;
        const int ko = (idx & 7) * 4;
        const int kg = k0 + ko;
        if (region == 0) {
          f16* dst = &lA[0][0] + r * 40 + ko;
          if (kg < IX) {
            if (XM == 1) {
              cvt4f(*(const float4*)((const float*)da.x + (size_t)(m0 + r) * a.xs + kg), dst);
            } else if (XM == 2) {
              unsigned r8 = *(const unsigned*)((const u8*)da.x + (size_t)(m0 + r) * a.xs + kg);
              union { f16 o[4]; uint2 q; } t;
#pragma unroll
              for (int j = 0; j < 4; ++j) t.o[j] = (f16)e4m3_to_f32((u8)(r8 >> (8 * j)));
              *(uint2*)dst = t.q;
            } else {
              *(uint2*)dst = *(const uint2*)((const f16*)da.x + (size_t)(m0 + r) * a.xs + kg);
            }
          } else {
            *(uint2*)dst = *(const uint2*)(da.hprev_h + (size_t)(m0 + r) * Hn + (kg - IX));
          }
        } else {
          const int g = region - 1;
          const int row = g * Hn + hc + r;
          const float* src = (kg < IX) ? (da.Wih + (size_t)row * IX + kg)
                                       : (da.Whh + (size_t)row * Hn + (kg - IX));
          cvt4f(*(const float4*)src, &lW[0][g][0] + r * 40 + ko);
        }
      }
      __syncthreads();
      f16x8 af = *(const f16x8*)(&lA[0][0] + (mi * 16 + fr) * 40 + fq * 8);
      f16x8 wr = *(const f16x8*)(&lW[0][0][0] + (ni * 16 + fr) * 40 + fq * 8);
      f16x8 wz = *(const f16x8*)(&lW[0][1][0] + (ni * 16 + fr) * 40 + fq * 8);
      f16x8 wn = *(const f16x8*)(&lW[0][2][0] + (ni * 16 + fr) * 40 + fq * 8);
      accR = MFMA16(af, wr, accR);
      accZ = MFMA16(af, wz, accZ);
      if (k0 < IX) accIN = MFMA16(af, wn, accIN);
      else accHN = MFMA16(af, wn, accHN);
      __syncthreads();
    }
  }

  if constexpr (WM == 1) {
    // Reduce ki=1 partials into ki=0 waves (wave w pairs with w+4: same mi,ni).
    __shared__ f32x4 red[4][64][4];
    if (ki == 1) {
      red[wave & 3][lane][0] = accR;
      red[wave & 3][lane][1] = accZ;
      red[wave & 3][lane][2] = accIN;
      red[wave & 3][lane][3] = accHN;
    }
    __syncthreads();
    if (ki == 1) return;
    accR += red[wave & 3][lane][0];
    accZ += red[wave & 3][lane][1];
    accIN += red[wave & 3][lane][2];
    accHN += red[wave & 3][lane][3];
  }

  const int k = hc + ni * 16 + fr;  // C/D: col(n)=lane&15, row(m)=(lane>>4)*4+reg
  const float br = da.bih[k] + da.bhh[k];
  const float bz = da.bih[Hn + k] + da.bhh[Hn + k];
  const float bin = da.bih[2 * Hn + k];
  const float bhn = da.bhh[2 * Hn + k];
#pragma unroll
  for (int r = 0; r < 4; ++r) {
    const int b = m0 + mi * 16 + fq * 4 + r;
    const float rg = sigm(accR[r] + br);
    const float zg = sigm(accZ[r] + bz);
    const float ng = tanhf(accIN[r] + bin + rg * (accHN[r] + bhn));
    const float hold = da.hprev_f[(size_t)b * Hn + k];
    const bool valid = (a.length == nullptr) || (da.t < a.length[b]);
    const float hnew = valid ? ((1.f - zg) * ng + zg * hold) : hold;
    da.hcur_f[(size_t)b * Hn + k] = hnew;
    da.hcur_h[(size_t)b * Hn + k] = tof16(hnew);
    if (YM == 1)
      ((f16*)da.yout)[(size_t)b * 2048 + k] = valid ? tof16(hnew) : (f16)0.f;
    else if (YM == 2)
      ((u8*)da.yout)[(size_t)b * 2048 + k] = f32_to_e4m3(valid ? hnew : 0.f);
  }
}

// Generic NT GEMM: C(128,N) = A(128,K) @ W^T + bias. A is internal f16; W is
// two stacked raw-fp32 blocks [W0 (nsplit rows); W1], converted in staging.
__global__ void __launch_bounds__(256) gemm_nt_kernel(
    const f16* __restrict__ A, const float* __restrict__ W0, const float* __restrict__ W1,
    const float* __restrict__ bias0, const float* __restrict__ bias1, int nsplit,
    float* __restrict__ Cout, int N, int K) {
  const int n0 = blockIdx.x * 64, m0 = blockIdx.y * 32;
  const int tid = threadIdx.x, wave = tid >> 6, lane = tid & 63;
  const int mi = wave >> 1, nj = wave & 1;
  const int fr = lane & 15, fq = lane >> 4;
  __shared__ alignas(16) f16 lA[32 * 40];
  __shared__ alignas(16) f16 lW[64 * 40];
  f32x4 acc0 = {0.f, 0.f, 0.f, 0.f}, acc1 = acc0;
  const int KT = K / 32;
#pragma unroll 1
  for (int kb = 0; kb < KT; ++kb) {
    const int k0 = kb * 32;
#pragma unroll
    for (int c = tid; c < 768; c += 256) {
      if (c < 256) {
        int r = c >> 3, ko = (c & 7) * 4;
        *(uint2*)(lA + r * 40 + ko) =
            *(const uint2*)(A + (size_t)(m0 + r) * K + k0 + ko);
      } else {
        int c2 = c - 256;
        int r = c2 >> 3, ko = (c2 & 7) * 4;
        int n = n0 + r;
        float4 v = {0.f, 0.f, 0.f, 0.f};
        if (n < N) {
          const float* src = (n < nsplit) ? (W0 + (size_t)n * K + k0 + ko)
                                          : (W1 + (size_t)(n - nsplit) * K + k0 + ko);
          v = *(const float4*)src;
        }
        cvt4f(v, lW + r * 40 + ko);
      }
    }
    __syncthreads();
    f16x8 af = *(const f16x8*)(lA + (mi * 16 + fr) * 40 + fq * 8);
    f16x8 w0 = *(const f16x8*)(lW + (nj * 32 + fr) * 40 + fq * 8);
    f16x8 w1 = *(const f16x8*)(lW + (nj * 32 + 16 + fr) * 40 + fq * 8);
    acc0 = MFMA16(af, w0, acc0);
    acc1 = MFMA16(af, w1, acc1);
    __syncthreads();
  }
#pragma unroll
  for (int j = 0; j < 2; ++j) {
    const f32x4 acc = j ? acc1 : acc0;
    const int n = n0 + nj * 32 + j * 16 + fr;
    if (n >= N) continue;
    const float bv = (n < nsplit) ? bias0[n] : bias1[n - nsplit];
#pragma unroll
    for (int r = 0; r < 4; ++r) {
      const int m = m0 + mi * 16 + fq * 4 + r;
      Cout[(size_t)m * N + n] = acc[r] + bv;
    }
  }
}

__global__ void build_hid(const f16* __restrict__ h0f, const f16* __restrict__ h0b,
                          const f16* __restrict__ h1f, const f16* __restrict__ h1b,
                          f16* __restrict__ hidf) {
  int i = blockIdx.x * 256 + threadIdx.x;
  if (i >= Bn * Hn) return;
  int b = i / Hn, k = i - b * Hn;
  f16* row = hidf + (size_t)b * 4096;
  row[k] = h0f[i];
  row[1024 + k] = h0b[i];
  row[2048 + k] = h1f[i];
  row[3072 + k] = h1b[i];
}

__global__ void z_kernel(const float* __restrict__ mulv, const float* __restrict__ eps,
                         f16* __restrict__ zcat, float* __restrict__ out_mu,
                         float* __restrict__ out_lv) {
  int i = blockIdx.x * 256 + threadIdx.x;
  if (i >= Bn * Ln) return;
  int b = i / Ln, j = i - b * Ln;
  float mu = mulv[(size_t)b * 512 + j];
  float lv = mulv[(size_t)b * 512 + 256 + j];
  float z = eps[i] * expf(0.5f * fminf(fmaxf(lv, -80.f), 80.f)) + mu;
  zcat[(size_t)b * ZDn + j] = tof16(z);
  out_mu[i] = mu;
  out_lv[i] = lv;
}

__global__ void zscatter(const float* __restrict__ zres, f16* __restrict__ xdec,
                         float* __restrict__ hdecf, f16* __restrict__ hdech) {
  int i = blockIdx.x * 256 + threadIdx.x;
  if (i >= Bn * 1120) return;
  int b = i / 1120, c = i - b * 1120;
  float v = zres[i];
  if (c < 96) {
    xdec[b * 192 + 96 + c] = tof16(v);
  } else {
    int k = c - 96;
    hdecf[(size_t)b * Hn + k] = v;
    hdech[(size_t)b * Hn + k] = tof16(v);
  }
}

// Logits stored fp32 directly into d_out's softmax region (overwritten
// in-place by softmax_kernel); argmax from fp32 LDS values.
__global__ void __launch_bounds__(256) outproj_kernel(
    const float* __restrict__ hdec, const float* __restrict__ Wout,
    const float* __restrict__ bout, float* __restrict__ logits,
    f16* __restrict__ xdec, int t) {
  const int b = blockIdx.x;
  const int tid = threadIdx.x, wave = tid >> 6, lane = tid & 63;
  __shared__ float hrow[Hn];
  __shared__ float chd[Cn];
  for (int i = tid; i < Hn; i += 256) hrow[i] = hdec[(size_t)b * Hn + i];
  __syncthreads();
  for (int n = wave; n < Cn; n += 4) {
    const float* wr = Wout + (size_t)n * Hn;
    float s = 0.f;
    for (int kk = lane; kk < Hn; kk += 64) s += hrow[kk] * wr[kk];
#pragma unroll
    for (int off = 32; off; off >>= 1) s += __shfl_down(s, off, 64);
    if (lane == 0) chd[n] = s + bout[n];
  }
  __syncthreads();
  float* lrow = logits + ((size_t)b * Tn + t) * Cn;
  for (int c = tid; c < Cn; c += 256) lrow[c] = chd[c];
  if (wave == 0) {
    float va = chd[lane];
    int ia = lane;
    if (lane < 32) {
      float vb = chd[64 + lane];
      if (vb > va) { va = vb; ia = 64 + lane; }
    }
#pragma unroll
    for (int off = 32; off; off >>= 1) {
      float vo = __shfl_down(va, off, 64);
      int io = __shfl_down(ia, off, 64);
      if (vo > va || (vo == va && io < ia)) { va = vo; ia = io; }
    }
    const int amax = __shfl(ia, 0, 64);  // first-occurrence argmax (np semantics)
    xdec[b * 192 + lane] = (f16)((lane == amax) ? 1.f : 0.f);
    if (lane < 32) xdec[b * 192 + 64 + lane] = (f16)((64 + lane == amax) ? 1.f : 0.f);
  }
}

__global__ void softmax_kernel(float* __restrict__ out) {
  const int row = blockIdx.x * 4 + (threadIdx.x >> 6);
  const int lane = threadIdx.x & 63;
  if (row >= Bn * Tn) return;
  float* lr = out + (size_t)row * Cn;    // fp32 logits, overwritten in place
  float v1 = lr[lane];
  float v2 = (lane < 32) ? lr[64 + lane] : -INFINITY;
  float m = fmaxf(v1, v2);
#pragma unroll
  for (int off = 32; off; off >>= 1) m = fmaxf(m, __shfl_xor(m, off, 64));
  float e1 = expf(v1 - m);
  float e2 = (lane < 32) ? expf(v2 - m) : 0.f;
  float s = e1 + e2;
#pragma unroll
  for (int off = 32; off; off >>= 1) s += __shfl_xor(s, off, 64);
  const float inv = 1.f / s, ls = logf(s);
  float* o1 = out + (size_t)OUT_SM + (size_t)row * Cn;
  lr[lane] = e1 * inv;
  o1[lane] = v1 - m - ls;
  if (lane < 32) {
    lr[64 + lane] = e2 * inv;
    o1[64 + lane] = v2 - m - ls;
  }
}

extern "C" void kernel_launch(void* const* d_in, const int* in_sizes, int n_in,
                              void* d_out, int out_size, void* d_ws, size_t ws_size,
                              hipStream_t stream) {
  (void)in_sizes; (void)n_in; (void)out_size;
  char* wsp = (char*)d_ws;
  size_t off = 0;
  auto alloc = [&](size_t bytes) -> void* {
    size_t o = (off + 255) & ~(size_t)255;
    off = o + bytes;
    return (void*)(wsp + o);
  };

  // Tier select on ws_size (constant per session -> graph-safe).
  const bool y16 = (ws_size >= 165000000ull);
  const size_t esz = y16 ? 2 : 1;      // y0 element bytes (f16 vs fp8 e4m3)

  char* y0 = (char*)alloc((size_t)Tn * Bn * 2048 * esz);   // ~136MB or ~68MB
  float* hf[5][2];
  f16* hh[5][2];
  for (int d = 0; d < 5; ++d)
    for (int p = 0; p < 2; ++p) {
      hf[d][p] = (float*)alloc((size_t)Bn * Hn * 4);
      hh[d][p] = (f16*)alloc((size_t)Bn * Hn * 2);
    }
  f16* zcat = (f16*)alloc((size_t)Bn * ZDn * 2);
  float* mulv_f = (float*)alloc((size_t)Bn * 512 * 4);
  float* zres_f = (float*)alloc((size_t)Bn * 1120 * 4);
  f16* hidf = (f16*)alloc((size_t)Bn * 4096 * 2);
  f16* xdec = (f16*)alloc((size_t)Bn * 192 * 2);

  // ---- f16 preconverted-weight cascade (graph-safe: ws_size only). ----
  f16 *W16_e1f = nullptr, *W16_e1b = nullptr;
  f16 *W16_e0f = nullptr, *W16_e0b = nullptr;
  f16 *W16_dec = nullptr;
  auto try_allocb = [&](size_t bytes) -> void* {
    size_t o = (off + 255) & ~(size_t)255;
    if (o + bytes > ws_size) return nullptr;
    off = o + bytes;
    return (void*)(wsp + o);
  };
  {
    const size_t e1b = (size_t)3 * Hn * 3072 * 2;   // KWP(2048+1024)=3072
    const size_t e0b = (size_t)3 * Hn * 1152 * 2;   // KWP(96+1024)=1152
    const size_t dcb = (size_t)3 * Hn * 1216 * 2;   // KWP(192+1024)=1216
    size_t save = off;
    f16* a1 = (f16*)try_allocb(e1b); f16* b1 = a1 ? (f16*)try_allocb(e1b) : nullptr;
    if (b1) { W16_e1f = a1; W16_e1b = b1; } else off = save;
    save = off;
    f16* a0 = (f16*)try_allocb(e0b); f16* b0 = a0 ? (f16*)try_allocb(e0b) : nullptr;
    if (b0) { W16_e0f = a0; W16_e0b = b0; } else off = save;
    save = off;
    f16* dc = (f16*)try_allocb(dcb);
    if (dc) W16_dec = dc; else off = save;
  }

  if (W16_e1f) {
    wconvert<<<dim3(3072), dim3(256), 0, stream>>>(
        (const float*)d_in[11], (const float*)d_in[12], 2048, 3072, W16_e1f);
    wconvert<<<dim3(3072), dim3(256), 0, stream>>>(
        (const float*)d_in[15], (const float*)d_in[16], 2048, 3072, W16_e1b);
  }
  if (W16_e0f) {
    wconvert<<<dim3(3072), dim3(256), 0, stream>>>(
        (const float*)d_in[3], (const float*)d_in[4], Cn, 1152, W16_e0f);
    wconvert<<<dim3(3072), dim3(256), 0, stream>>>(
        (const float*)d_in[7], (const float*)d_in[8], Cn, 1152, W16_e0b);
  }
  if (W16_dec)
    wconvert<<<dim3(3072), dim3(256), 0, stream>>>(
        (const float*)d_in[28], (const float*)d_in[29], 192, 1216, W16_dec);

  init_kernel<<<dim3(512), dim3(256), 0, stream>>>(
      hf[0][0], hf[1][0], hf[2][0], hf[3][0],
      hh[0][0], hh[1][0], hh[2][0], hh[3][0],
      xdec, (const float*)d_in[27]);
  melody_fill<<<dim3((MELn / 4 + 255) / 256, Bn), dim3(256), 0, stream>>>(
      (const float*)d_in[1], zcat);

  const int* lenp = (const int*)d_in[34];

  // ---- encoder layer 0 (bidirectional, fused fwd+bwd per launch) ----
  for (int s = 0; s < Tn; ++s) {
    StepArgs a{};
    const int tf = s, tb = Tn - 1 - s;
    const int p = s & 1, q = (s + 1) & 1;
    a.d[0].x = (const float*)d_in[0] + (size_t)tf * Cn;
    a.d[0].Wih = (const float*)d_in[3]; a.d[0].Whh = (const float*)d_in[4];
    a.d[0].bih = (const float*)d_in[5]; a.d[0].bhh = (const float*)d_in[6];
    a.d[0].W16 = W16_e0f;
    a.d[0].hprev_f = hf[0][p]; a.d[0].hprev_h = hh[0][p];
    a.d[0].hcur_f = hf[0][q]; a.d[0].hcur_h = hh[0][q];
    a.d[0].yout = y0 + (size_t)tf * Bn * 2048 * esz;
    a.d[0].t = tf;
    a.d[1].x = (const float*)d_in[0] + (size_t)tb * Cn;
    a.d[1].Wih = (const float*)d_in[7]; a.d[1].Whh = (const float*)d_in[8];
    a.d[1].bih = (const float*)d_in[9]; a.d[1].bhh = (const float*)d_in[10];
    a.d[1].W16 = W16_e0b;
    a.d[1].hprev_f = hf[1][p]; a.d[1].hprev_h = hh[1][p];
    a.d[1].hcur_f = hf[1][q]; a.d[1].hcur_h = hh[1][q];
    a.d[1].yout = y0 + ((size_t)tb * Bn * 2048 + Hn) * esz;
    a.d[1].t = tb;
    a.length = lenp;
    a.xs = Tn * Cn;   // input_x is (B,T,C): batch stride T*C
    if (y16) {
      if (W16_e0f) gru_step_kernel<Cn, 1, 1, 1><<<dim3(32, 4, 2), dim3(512), 0, stream>>>(a);
      else         gru_step_kernel<Cn, 1, 1, 0><<<dim3(32, 4, 2), dim3(256), 0, stream>>>(a);
    } else {
      if (W16_e0f) gru_step_kernel<Cn, 1, 2, 1><<<dim3(32, 4, 2), dim3(512), 0, stream>>>(a);
      else         gru_step_kernel<Cn, 1, 2, 0><<<dim3(32, 4, 2), dim3(256), 0, stream>>>(a);
    }
  }
  // ---- encoder layer 1 ----
  for (int s = 0; s < Tn; ++s) {
    StepArgs a{};
    const int tf = s, tb = Tn - 1 - s;
    const int p = s & 1, q = (s + 1) & 1;
    a.d[0].x = y0 + (size_t)tf * Bn * 2048 * esz;
    a.d[0].Wih = (const float*)d_in[11]; a.d[0].Whh = (const float*)d_in[12];
    a.d[0].bih = (const float*)d_in[13]; a.d[0].bhh = (const float*)d_in[14];
    a.d[0].W16 = W16_e1f;
    a.d[0].hprev_f = hf[2][p]; a.d[0].hprev_h = hh[2][p];
    a.d[0].hcur_f = hf[2][q]; a.d[0].hcur_h = hh[2][q];
    a.d[0].yout = nullptr;
    a.d[0].t = tf;
    a.d[1].x = y0 + (size_t)tb * Bn * 2048 * esz;
    a.d[1].Wih = (const float*)d_in[15]; a.d[1].Whh = (const float*)d_in[16];
    a.d[1].bih = (const float*)d_in[17]; a.d[1].bhh = (const float*)d_in[18];
    a.d[1].W16 = W16_e1b;
    a.d[1].hprev_f = hf[3][p]; a.d[1].hprev_h = hh[3][p];
    a.d[1].hcur_f = hf[3][q]; a.d[1].hcur_h = hh[3][q];
    a.d[1].yout = nullptr;
    a.d[1].t = tb;
    a.length = lenp;
    a.xs = 2048;
    if (y16) {
      if (W16_e1f) gru_step_kernel<2048, 0, 0, 1><<<dim3(32, 4, 2), dim3(512), 0, stream>>>(a);
      else         gru_step_kernel<2048, 0, 0, 0><<<dim3(32, 4, 2), dim3(256), 0, stream>>>(a);
    } else {
      if (W16_e1f) gru_step_kernel<2048, 2, 0, 1><<<dim3(32, 4, 2), dim3(512), 0, stream>>>(a);
      else         gru_step_kernel<2048, 2, 0, 0><<<dim3(32, 4, 2), dim3(256), 0, stream>>>(a);
    }
  }

  // ---- VAE mid-section ----
  build_hid<<<dim3((Bn * Hn + 255) / 256), dim3(256), 0, stream>>>(
      hh[0][0], hh[1][0], hh[2][0], hh[3][0], hidf);
  gemm_nt_kernel<<<dim3(8, 4), dim3(256), 0, stream>>>(
      hidf, (const float*)d_in[19], (const float*)d_in[21],
      (const float*)d_in[20], (const float*)d_in[22], 256, mulv_f, 512, 4096);
  float* outp = (float*)d_out;
  z_kernel<<<dim3((Bn * Ln + 255) / 256), dim3(256), 0, stream>>>(
      mulv_f, (const float*)d_in[2], zcat,
      outp + 2 * (size_t)OUT_SM, outp + 2 * (size_t)OUT_SM + Bn * Ln);
  gemm_nt_kernel<<<dim3(18, 4), dim3(256), 0, stream>>>(
      zcat, (const float*)d_in[23], (const float*)d_in[25],
      (const float*)d_in[24], (const float*)d_in[26], 96, zres_f, 1120, ZDn);
  zscatter<<<dim3((Bn * 1120 + 255) / 256), dim3(256), 0, stream>>>(
      zres_f, xdec, hf[4][0], hh[4][0]);

  // ---- autoregressive decoder ----
  for (int s = 0; s < Tn; ++s) {
    StepArgs a{};
    const int p = s & 1, q = (s + 1) & 1;
    a.d[0].x = xdec;
    a.d[0].Wih = (const float*)d_in[28]; a.d[0].Whh = (const float*)d_in[29];
    a.d[0].bih = (const float*)d_in[30]; a.d[0].bhh = (const float*)d_in[31];
    a.d[0].W16 = W16_dec;
    a.d[0].hprev_f = hf[4][p]; a.d[0].hprev_h = hh[4][p];
    a.d[0].hcur_f = hf[4][q]; a.d[0].hcur_h = hh[4][q];
    a.d[0].yout = nullptr;
    a.d[0].t = s;
    a.d[1] = a.d[0];
    a.length = nullptr;  // decoder: no masking
    a.xs = 192;
    if (W16_dec) gru_step_kernel<192, 0, 0, 1><<<dim3(32, 4, 1), dim3(512), 0, stream>>>(a);
    else         gru_step_kernel<192, 0, 0, 0><<<dim3(32, 4, 1), dim3(256), 0, stream>>>(a);
    outproj_kernel<<<dim3(Bn), dim3(256), 0, stream>>>(
        hf[4][q], (const float*)d_in[32], (const float*)d_in[33],
        outp, xdec, s);
  }

  softmax_kernel<<<dim3((Bn * Tn + 3) / 4), dim3(256), 0, stream>>>(outp);
}

// Round 7
// 28174.060 us; speedup vs baseline: 1.8682x; 1.2895x over previous
//
#include <hip/hip_runtime.h>
#include <hip/hip_bf16.h>

typedef _Float16 f16;
typedef unsigned short u16;
typedef unsigned char u8;
typedef __attribute__((ext_vector_type(8))) _Float16 f16x8;
typedef __attribute__((ext_vector_type(4))) float f32x4;

#define DI __device__ __forceinline__
#define MFMA16(A, B, C) __builtin_amdgcn_mfma_f32_16x16x32_f16(A, B, C, 0, 0, 0)

constexpr int Bn = 128, Tn = 272, Cn = 96, Hn = 1024, Ln = 256;
constexpr int MELn = 26112, ZDn = 26368;
constexpr int OUT_SM = Bn * Tn * Cn;  // 3342336

DI float sigm(float x) { return 1.f / (1.f + expf(-x)); }
// Clamped narrowing: nothing can become inf/NaN.
DI f16 tof16(float x) { return (f16)fminf(fmaxf(x, -60000.f), 60000.f); }

// 4 fp32 -> 4 f16, 8B store.
DI void cvt4f(float4 v, f16* dst) {
  union { f16 o[4]; uint2 q; } t;
  t.o[0] = tof16(v.x); t.o[1] = tof16(v.y); t.o[2] = tof16(v.z); t.o[3] = tof16(v.w);
  *(uint2*)dst = t.q;
}

// ---- fp8 e4m3fn via bit math (y0 compression fallback for small ws) ----
DI u8 f32_to_e4m3(float x) {
  union { float f; unsigned u; } v; v.f = x;
  unsigned s = (v.u >> 31) << 7;
  float a = fabsf(x);
  if (!(a >= 0.015625f)) {              // subnormal / zero region (a < 2^-6)
    int m = (int)(a * 512.0f + 0.5f);   // ulp = 2^-9
    return (u8)(s | m);
  }
  if (a > 448.f) return (u8)(s | 0x7E);
  v.f = a;
  unsigned e = (v.u >> 23) & 0xFF;
  unsigned mant = (v.u & 0x7FFFFF) + (1u << 19);
  if (mant >> 23) { mant = 0; e += 1; }
  unsigned e8 = e - 120;
  return (u8)(s | (e8 << 3) | (mant >> 20));
}
DI float e4m3_to_f32(u8 b) {
  unsigned s = b >> 7, e = (b >> 3) & 15, m = b & 7;
  float v;
  if (e == 0) v = (float)m * 0.001953125f;
  else { union { unsigned u; float f; } t; t.u = ((e + 120) << 23) | (m << 20); v = t.f; }
  return s ? -v : v;
}

__global__ void melody_fill(const float* __restrict__ mel, f16* __restrict__ zcat) {
  int i = blockIdx.x * 256 + threadIdx.x;
  int b = blockIdx.y;
  if (i < MELn / 4)
    cvt4f(((const float4*)(mel + (size_t)b * MELn))[i],
          zcat + (size_t)b * ZDn + Ln + (size_t)i * 4);
}

__global__ void init_kernel(float* h0, float* h1, float* h2, float* h3,
                            f16* g0, f16* g1, f16* g2, f16* g3,
                            f16* xdec, const float* init_tok) {
  int i = blockIdx.x * 256 + threadIdx.x;
  if (i < Bn * Hn) {
    h0[i] = 0.f; h1[i] = 0.f; h2[i] = 0.f; h3[i] = 0.f;
    g0[i] = (f16)0.f; g1[i] = (f16)0.f; g2[i] = (f16)0.f; g3[i] = (f16)0.f;
  }
  if (i < Bn * Cn) {
    int b = i / Cn, c = i - b * Cn;
    xdec[b * 192 + c] = tof16(init_tok[c]);
  }
}

// One-shot: W16[3H][KWP] = f16(concat(Wih, Whh)) row-major, zero-padded to
// KWP (multiple of 64). Same tof16 as staging -> bit-identical numerics.
__global__ void wconvert(const float* __restrict__ Wih, const float* __restrict__ Whh,
                         int IX, int KWP, f16* __restrict__ W16) {
  const int KW = IX + Hn;
  const int row = blockIdx.x;
  const float* srcI = Wih + (size_t)row * IX;
  const float* srcH = Whh + (size_t)row * Hn;
  f16* dst = W16 + (size_t)row * KWP;
  for (int j = threadIdx.x * 8; j < KWP; j += 256 * 8) {
    union { f16 o[8]; uint4 q; } t;
    if (j < KW) {  // IX%8==0, KW%8==0: chunks never straddle boundaries
      const float* s = (j < IX) ? (srcI + j) : (srcH + (j - IX));
      float4 v0 = *(const float4*)s, v1 = *(const float4*)(s + 4);
      t.o[0] = tof16(v0.x); t.o[1] = tof16(v0.y); t.o[2] = tof16(v0.z); t.o[3] = tof16(v0.w);
      t.o[4] = tof16(v1.x); t.o[5] = tof16(v1.y); t.o[6] = tof16(v1.z); t.o[7] = tof16(v1.w);
    } else {
      t.q = uint4{0, 0, 0, 0};
    }
    *(uint4*)(dst + j) = t.q;
  }
}

struct DirArgs {
  const void* x;      // XM=0: f16, XM=1: fp32, XM=2: fp8
  const float* Wih;   // raw fp32 weights (WM=0 path)
  const float* Whh;
  const f16* W16;     // preconverted concat weights, KWP-padded
  const float* bih;
  const float* bhh;
  const float* hprev_f;
  const f16* hprev_h;
  float* hcur_f;
  f16* hcur_h;
  void* yout;   // layer-0 output base (already offset t*B*2048 + dir*H, in elts)
  int t;
};
struct StepArgs {
  DirArgs d[2];
  const int* length;  // null -> no masking (decoder)
  int xs;             // x row stride in ELEMENTS
};

// Fused GRU step (r3-proven structure). 32 batch x 32 h-cols per block.
// XM: x dtype (0=f16,1=fp32,2=fp8). YM: y0 store (0=none,1=f16,2=fp8).
// WM=0: legacy fp32-weight staging, 256 thr / 4 waves, 32-K steps, 2 barriers.
// WM=1: preconverted f16 weights, 512 thr / 8 waves, 64-K steps, K-half split
//       across wave pairs (ki), double-buffered LDS, and a DEPTH-2 register
//       pipeline: ld(it+2) issued at iter it, stored at iter it+1 -> loads
//       stay in flight for a full iteration (MFMA+barrier+MFMA) instead of
//       ~50cy. Two named register sets (no runtime-indexed reg arrays).
template <int IX, int XM, int YM, int WM>
__global__ void __launch_bounds__(WM == 1 ? 512 : 256) gru_step_kernel(StepArgs a) {
  constexpr int KW = IX + Hn;
  constexpr int KWP = (KW + 63) & ~63;
  constexpr int KT = KW / 32;          // legacy 32-K step count (KW%32==0)
  constexpr int NT = KWP / 64;         // WM1 64-K step count
  const DirArgs da = a.d[blockIdx.z];
  const int hc = blockIdx.x * 32;
  const int m0 = blockIdx.y * 32;
  const int tid = threadIdx.x;
  const int wave = tid >> 6, lane = tid & 63;
  const int ki = wave >> 2;
  const int mi = (wave >> 1) & 1, ni = wave & 1;
  const int fr = lane & 15, fq = lane >> 4;

  // Double-buffered (WM1). Legacy WM0 uses buffer 0 with 40-stride only.
  __shared__ alignas(16) f16 lA[2][32 * 72];
  __shared__ alignas(16) f16 lW[2][3][32 * 72];

  f32x4 accR = {0.f, 0.f, 0.f, 0.f};
  f32x4 accZ = accR, accIN = accR, accHN = accR;

  if constexpr (WM == 1) {
    const int idx0 = tid & 255;
    const int r0 = idx0 >> 3;            // 0..31 row
    const int ko0 = (idx0 & 7) * 8;      // 0..56 f16 col within 64-K tile
    const bool loA = (tid < 256);
    const f16* wb0 = da.W16 + (size_t)(hc + r0) * KWP + ko0;                    // gate0 (!loA)
    const f16* wb1 = da.W16 + (size_t)((loA ? 1 : 2) * Hn + hc + r0) * KWP + ko0;
    // staging dsts, both buffers
    f16* d0_0 = loA ? (&lA[0][0] + r0 * 72 + ko0) : (&lW[0][0][0] + r0 * 72 + ko0);
    f16* d0_1 = loA ? (&lA[1][0] + r0 * 72 + ko0) : (&lW[1][0][0] + r0 * 72 + ko0);
    f16* d1_0 = &lW[0][loA ? 1 : 2][0] + r0 * 72 + ko0;
    f16* d1_1 = &lW[1][loA ? 1 : 2][0] + r0 * 72 + ko0;
    const f16* hrow = da.hprev_h + (size_t)(m0 + r0) * Hn;
    const f16* xrow_h = (const f16*)da.x + (size_t)(m0 + r0) * a.xs;
    const float* xrow_f = (const float*)da.x + (size_t)(m0 + r0) * a.xs;
    const u8* xrow_8 = (const u8*)da.x + (size_t)(m0 + r0) * a.xs;
    // fragment ptrs, both buffers
    const int fofA = (mi * 16 + fr) * 72 + ki * 32 + fq * 8;
    const int fofW = (ni * 16 + fr) * 72 + ki * 32 + fq * 8;
    const f16* pA0 = &lA[0][0] + fofA;   const f16* pA1 = &lA[1][0] + fofA;
    const f16* pW00 = &lW[0][0][0] + fofW; const f16* pW01 = &lW[1][0][0] + fofW;
    const f16* pW10 = &lW[0][1][0] + fofW; const f16* pW11 = &lW[1][1][0] + fofW;
    const f16* pW20 = &lW[0][2][0] + fofW; const f16* pW21 = &lW[1][2][0] + fofW;

    // Two named register sets (depth-2 pipeline). Tile T lives in set T&1.
    uint4 rA_0{0,0,0,0}, r1_0{0,0,0,0}, rA_1{0,0,0,0}, r1_1{0,0,0,0};
    float4 rx0_0{}, rx1_0{}, rx0_1{}, rx1_1{};
    uint2 r8x_0{}, r8x_1{};

    auto ldt = [&](int it, uint4& rA, uint4& r1, float4& rx0, float4& rx1, uint2& r8x) {
      const int kg = it * 64 + ko0;
      if (loA) {
        if (kg < IX) {
          if (XM == 1) {
            rx0 = *(const float4*)(xrow_f + kg);
            rx1 = *(const float4*)(xrow_f + kg + 4);
          } else if (XM == 2) {
            r8x = *(const uint2*)(xrow_8 + kg);
          } else {
            rA = *(const uint4*)(xrow_h + kg);
          }
        } else if (kg < KW) {
          rA = *(const uint4*)(hrow + (kg - IX));
        } else {
          rA = uint4{0, 0, 0, 0};        // zero-pad tail
        }
      } else {
        rA = *(const uint4*)(wb0 + it * 64);
      }
      r1 = *(const uint4*)(wb1 + it * 64);
    };
    auto stt = [&](int it, bool buf1, uint4& rA, uint4& r1, float4& rx0, float4& rx1,
                   uint2& r8x) {
      f16* d0 = buf1 ? d0_1 : d0_0;
      f16* d1 = buf1 ? d1_1 : d1_0;
      const int kg = it * 64 + ko0;
      if (loA && XM == 1 && kg < IX) {
        union { f16 o[8]; uint4 q; } t;
        t.o[0] = tof16(rx0.x); t.o[1] = tof16(rx0.y);
        t.o[2] = tof16(rx0.z); t.o[3] = tof16(rx0.w);
        t.o[4] = tof16(rx1.x); t.o[5] = tof16(rx1.y);
        t.o[6] = tof16(rx1.z); t.o[7] = tof16(rx1.w);
        *(uint4*)d0 = t.q;
      } else if (loA && XM == 2 && kg < IX) {
        union { f16 o[8]; uint4 q; } t;
#pragma unroll
        for (int j = 0; j < 4; ++j) t.o[j] = (f16)e4m3_to_f32((u8)(r8x.x >> (8 * j)));
#pragma unroll
        for (int j = 0; j < 4; ++j) t.o[4 + j] = (f16)e4m3_to_f32((u8)(r8x.y >> (8 * j)));
        *(uint4*)d0 = t.q;
      } else {
        *(uint4*)d0 = rA;
      }
      *(uint4*)d1 = r1;
    };

    // prologue: tile0 -> buf0; tile1 loads in flight across the barrier
    ldt(0, rA_0, r1_0, rx0_0, rx1_0, r8x_0);
    stt(0, false, rA_0, r1_0, rx0_0, rx1_0, r8x_0);
    if (NT > 1) ldt(1, rA_1, r1_1, rx0_1, rx1_1, r8x_1);
    __syncthreads();

    int it = 0;
    while (true) {
      // even tile: compute buf0; store tile it+1 (set1) -> buf1; prefetch it+2 -> set0
      if (it + 2 < NT) ldt(it + 2, rA_0, r1_0, rx0_0, rx1_0, r8x_0);
      {
        f16x8 af = *(const f16x8*)pA0;
        f16x8 wr = *(const f16x8*)pW00;
        f16x8 wz = *(const f16x8*)pW10;
        f16x8 wn = *(const f16x8*)pW20;
        accR = MFMA16(af, wr, accR);
        accZ = MFMA16(af, wz, accZ);
        const int kgw = it * 64 + ki * 32;
        if (kgw < IX) accIN = MFMA16(af, wn, accIN);
        else accHN = MFMA16(af, wn, accHN);
      }
      if (it + 1 < NT) stt(it + 1, true, rA_1, r1_1, rx0_1, rx1_1, r8x_1);
      __syncthreads();
      if (++it >= NT) break;
      // odd tile: compute buf1; store tile it+1 (set0) -> buf0; prefetch it+2 -> set1
      if (it + 2 < NT) ldt(it + 2, rA_1, r1_1, rx0_1, rx1_1, r8x_1);
      {
        f16x8 af = *(const f16x8*)pA1;
        f16x8 wr = *(const f16x8*)pW01;
        f16x8 wz = *(const f16x8*)pW11;
        f16x8 wn = *(const f16x8*)pW21;
        accR = MFMA16(af, wr, accR);
        accZ = MFMA16(af, wz, accZ);
        const int kgw = it * 64 + ki * 32;
        if (kgw < IX) accIN = MFMA16(af, wn, accIN);
        else accHN = MFMA16(af, wn, accHN);
      }
      if (it + 1 < NT) stt(it + 1, false, rA_0, r1_0, rx0_0, rx1_0, r8x_0);
      __syncthreads();
      if (++it >= NT) break;
    }
  } else {
    // ---- legacy fp32-weight staging path (256 threads, buffer 0) ----
#pragma unroll 1
    for (int kb = 0; kb < KT; ++kb) {
      const int k0 = kb * 32;
#pragma unroll
      for (int c = tid; c < 1024; c += 256) {
        const int region = c >> 8;
        const int idx = c & 255;
        const int r = idx >> 3;
        const int ko = (idx & 7) * 4;
        const int kg = k0 + ko;
        if (region == 0) {
          f16* dst = &lA[0][0] + r * 40 + ko;
          if (kg < IX) {
            if (XM == 1) {
              cvt4f(*(const float4*)((const float*)da.x + (size_t)(m0 + r) * a.xs + kg), dst);
            } else if (XM == 2) {
              unsigned r8 = *(const unsigned*)((const u8*)da.x + (size_t)(m0 + r) * a.xs + kg);
              union { f16 o[4]; uint2 q; } t;
#pragma unroll
              for (int j = 0; j < 4; ++j) t.o[j] = (f16)e4m3_to_f32((u8)(r8 >> (8 * j)));
              *(uint2*)dst = t.q;
            } else {
              *(uint2*)dst = *(const uint2*)((const f16*)da.x + (size_t)(m0 + r) * a.xs + kg);
            }
          } else {
            *(uint2*)dst = *(const uint2*)(da.hprev_h + (size_t)(m0 + r) * Hn + (kg - IX));
          }
        } else {
          const int g = region - 1;
          const int row = g * Hn + hc + r;
          const float* src = (kg < IX) ? (da.Wih + (size_t)row * IX + kg)
                                       : (da.Whh + (size_t)row * Hn + (kg - IX));
          cvt4f(*(const float4*)src, &lW[0][g][0] + r * 40 + ko);
        }
      }
      __syncthreads();
      f16x8 af = *(const f16x8*)(&lA[0][0] + (mi * 16 + fr) * 40 + fq * 8);
      f16x8 wr = *(const f16x8*)(&lW[0][0][0] + (ni * 16 + fr) * 40 + fq * 8);
      f16x8 wz = *(const f16x8*)(&lW[0][1][0] + (ni * 16 + fr) * 40 + fq * 8);
      f16x8 wn = *(const f16x8*)(&lW[0][2][0] + (ni * 16 + fr) * 40 + fq * 8);
      accR = MFMA16(af, wr, accR);
      accZ = MFMA16(af, wz, accZ);
      if (k0 < IX) accIN = MFMA16(af, wn, accIN);
      else accHN = MFMA16(af, wn, accHN);
      __syncthreads();
    }
  }

  if constexpr (WM == 1) {
    // Reduce ki=1 partials into ki=0 waves (wave w pairs with w+4: same mi,ni).
    __shared__ f32x4 red[4][64][4];
    if (ki == 1) {
      red[wave & 3][lane][0] = accR;
      red[wave & 3][lane][1] = accZ;
      red[wave & 3][lane][2] = accIN;
      red[wave & 3][lane][3] = accHN;
    }
    __syncthreads();
    if (ki == 1) return;
    accR += red[wave & 3][lane][0];
    accZ += red[wave & 3][lane][1];
    accIN += red[wave & 3][lane][2];
    accHN += red[wave & 3][lane][3];
  }

  const int k = hc + ni * 16 + fr;  // C/D: col(n)=lane&15, row(m)=(lane>>4)*4+reg
  const float br = da.bih[k] + da.bhh[k];
  const float bz = da.bih[Hn + k] + da.bhh[Hn + k];
  const float bin = da.bih[2 * Hn + k];
  const float bhn = da.bhh[2 * Hn + k];
#pragma unroll
  for (int r = 0; r < 4; ++r) {
    const int b = m0 + mi * 16 + fq * 4 + r;
    const float rg = sigm(accR[r] + br);
    const float zg = sigm(accZ[r] + bz);
    const float ng = tanhf(accIN[r] + bin + rg * (accHN[r] + bhn));
    const float hold = da.hprev_f[(size_t)b * Hn + k];
    const bool valid = (a.length == nullptr) || (da.t < a.length[b]);
    const float hnew = valid ? ((1.f - zg) * ng + zg * hold) : hold;
    da.hcur_f[(size_t)b * Hn + k] = hnew;
    da.hcur_h[(size_t)b * Hn + k] = tof16(hnew);
    if (YM == 1)
      ((f16*)da.yout)[(size_t)b * 2048 + k] = valid ? tof16(hnew) : (f16)0.f;
    else if (YM == 2)
      ((u8*)da.yout)[(size_t)b * 2048 + k] = f32_to_e4m3(valid ? hnew : 0.f);
  }
}

// Generic NT GEMM: C(128,N) = A(128,K) @ W^T + bias. A is internal f16; W is
// two stacked raw-fp32 blocks [W0 (nsplit rows); W1], converted in staging.
__global__ void __launch_bounds__(256) gemm_nt_kernel(
    const f16* __restrict__ A, const float* __restrict__ W0, const float* __restrict__ W1,
    const float* __restrict__ bias0, const float* __restrict__ bias1, int nsplit,
    float* __restrict__ Cout, int N, int K) {
  const int n0 = blockIdx.x * 64, m0 = blockIdx.y * 32;
  const int tid = threadIdx.x, wave = tid >> 6, lane = tid & 63;
  const int mi = wave >> 1, nj = wave & 1;
  const int fr = lane & 15, fq = lane >> 4;
  __shared__ alignas(16) f16 lA[32 * 40];
  __shared__ alignas(16) f16 lW[64 * 40];
  f32x4 acc0 = {0.f, 0.f, 0.f, 0.f}, acc1 = acc0;
  const int KT = K / 32;
#pragma unroll 1
  for (int kb = 0; kb < KT; ++kb) {
    const int k0 = kb * 32;
#pragma unroll
    for (int c = tid; c < 768; c += 256) {
      if (c < 256) {
        int r = c >> 3, ko = (c & 7) * 4;
        *(uint2*)(lA + r * 40 + ko) =
            *(const uint2*)(A + (size_t)(m0 + r) * K + k0 + ko);
      } else {
        int c2 = c - 256;
        int r = c2 >> 3, ko = (c2 & 7) * 4;
        int n = n0 + r;
        float4 v = {0.f, 0.f, 0.f, 0.f};
        if (n < N) {
          const float* src = (n < nsplit) ? (W0 + (size_t)n * K + k0 + ko)
                                          : (W1 + (size_t)(n - nsplit) * K + k0 + ko);
          v = *(const float4*)src;
        }
        cvt4f(v, lW + r * 40 + ko);
      }
    }
    __syncthreads();
    f16x8 af = *(const f16x8*)(lA + (mi * 16 + fr) * 40 + fq * 8);
    f16x8 w0 = *(const f16x8*)(lW + (nj * 32 + fr) * 40 + fq * 8);
    f16x8 w1 = *(const f16x8*)(lW + (nj * 32 + 16 + fr) * 40 + fq * 8);
    acc0 = MFMA16(af, w0, acc0);
    acc1 = MFMA16(af, w1, acc1);
    __syncthreads();
  }
#pragma unroll
  for (int j = 0; j < 2; ++j) {
    const f32x4 acc = j ? acc1 : acc0;
    const int n = n0 + nj * 32 + j * 16 + fr;
    if (n >= N) continue;
    const float bv = (n < nsplit) ? bias0[n] : bias1[n - nsplit];
#pragma unroll
    for (int r = 0; r < 4; ++r) {
      const int m = m0 + mi * 16 + fq * 4 + r;
      Cout[(size_t)m * N + n] = acc[r] + bv;
    }
  }
}

__global__ void build_hid(const f16* __restrict__ h0f, const f16* __restrict__ h0b,
                          const f16* __restrict__ h1f, const f16* __restrict__ h1b,
                          f16* __restrict__ hidf) {
  int i = blockIdx.x * 256 + threadIdx.x;
  if (i >= Bn * Hn) return;
  int b = i / Hn, k = i - b * Hn;
  f16* row = hidf + (size_t)b * 4096;
  row[k] = h0f[i];
  row[1024 + k] = h0b[i];
  row[2048 + k] = h1f[i];
  row[3072 + k] = h1b[i];
}

__global__ void z_kernel(const float* __restrict__ mulv, const float* __restrict__ eps,
                         f16* __restrict__ zcat, float* __restrict__ out_mu,
                         float* __restrict__ out_lv) {
  int i = blockIdx.x * 256 + threadIdx.x;
  if (i >= Bn * Ln) return;
  int b = i / Ln, j = i - b * Ln;
  float mu = mulv[(size_t)b * 512 + j];
  float lv = mulv[(size_t)b * 512 + 256 + j];
  float z = eps[i] * expf(0.5f * fminf(fmaxf(lv, -80.f), 80.f)) + mu;
  zcat[(size_t)b * ZDn + j] = tof16(z);
  out_mu[i] = mu;
  out_lv[i] = lv;
}

__global__ void zscatter(const float* __restrict__ zres, f16* __restrict__ xdec,
                         float* __restrict__ hdecf, f16* __restrict__ hdech) {
  int i = blockIdx.x * 256 + threadIdx.x;
  if (i >= Bn * 1120) return;
  int b = i / 1120, c = i - b * 1120;
  float v = zres[i];
  if (c < 96) {
    xdec[b * 192 + 96 + c] = tof16(v);
  } else {
    int k = c - 96;
    hdecf[(size_t)b * Hn + k] = v;
    hdech[(size_t)b * Hn + k] = tof16(v);
  }
}

// Logits stored fp32 directly into d_out's softmax region (overwritten
// in-place by softmax_kernel); argmax from fp32 LDS values.
__global__ void __launch_bounds__(256) outproj_kernel(
    const float* __restrict__ hdec, const float* __restrict__ Wout,
    const float* __restrict__ bout, float* __restrict__ logits,
    f16* __restrict__ xdec, int t) {
  const int b = blockIdx.x;
  const int tid = threadIdx.x, wave = tid >> 6, lane = tid & 63;
  __shared__ float hrow[Hn];
  __shared__ float chd[Cn];
  for (int i = tid; i < Hn; i += 256) hrow[i] = hdec[(size_t)b * Hn + i];
  __syncthreads();
  for (int n = wave; n < Cn; n += 4) {
    const float* wr = Wout + (size_t)n * Hn;
    float s = 0.f;
    for (int kk = lane; kk < Hn; kk += 64) s += hrow[kk] * wr[kk];
#pragma unroll
    for (int off = 32; off; off >>= 1) s += __shfl_down(s, off, 64);
    if (lane == 0) chd[n] = s + bout[n];
  }
  __syncthreads();
  float* lrow = logits + ((size_t)b * Tn + t) * Cn;
  for (int c = tid; c < Cn; c += 256) lrow[c] = chd[c];
  if (wave == 0) {
    float va = chd[lane];
    int ia = lane;
    if (lane < 32) {
      float vb = chd[64 + lane];
      if (vb > va) { va = vb; ia = 64 + lane; }
    }
#pragma unroll
    for (int off = 32; off; off >>= 1) {
      float vo = __shfl_down(va, off, 64);
      int io = __shfl_down(ia, off, 64);
      if (vo > va || (vo == va && io < ia)) { va = vo; ia = io; }
    }
    const int amax = __shfl(ia, 0, 64);  // first-occurrence argmax (np semantics)
    xdec[b * 192 + lane] = (f16)((lane == amax) ? 1.f : 0.f);
    if (lane < 32) xdec[b * 192 + 64 + lane] = (f16)((64 + lane == amax) ? 1.f : 0.f);
  }
}

__global__ void softmax_kernel(float* __restrict__ out) {
  const int row = blockIdx.x * 4 + (threadIdx.x >> 6);
  const int lane = threadIdx.x & 63;
  if (row >= Bn * Tn) return;
  float* lr = out + (size_t)row * Cn;    // fp32 logits, overwritten in place
  float v1 = lr[lane];
  float v2 = (lane < 32) ? lr[64 + lane] : -INFINITY;
  float m = fmaxf(v1, v2);
#pragma unroll
  for (int off = 32; off; off >>= 1) m = fmaxf(m, __shfl_xor(m, off, 64));
  float e1 = expf(v1 - m);
  float e2 = (lane < 32) ? expf(v2 - m) : 0.f;
  float s = e1 + e2;
#pragma unroll
  for (int off = 32; off; off >>= 1) s += __shfl_xor(s, off, 64);
  const float inv = 1.f / s, ls = logf(s);
  float* o1 = out + (size_t)OUT_SM + (size_t)row * Cn;
  lr[lane] = e1 * inv;
  o1[lane] = v1 - m - ls;
  if (lane < 32) {
    lr[64 + lane] = e2 * inv;
    o1[64 + lane] = v2 - m - ls;
  }
}

extern "C" void kernel_launch(void* const* d_in, const int* in_sizes, int n_in,
                              void* d_out, int out_size, void* d_ws, size_t ws_size,
                              hipStream_t stream) {
  (void)in_sizes; (void)n_in; (void)out_size;
  char* wsp = (char*)d_ws;
  size_t off = 0;
  auto alloc = [&](size_t bytes) -> void* {
    size_t o = (off + 255) & ~(size_t)255;
    off = o + bytes;
    return (void*)(wsp + o);
  };

  // Tier select on ws_size (constant per session -> graph-safe).
  const bool y16 = (ws_size >= 165000000ull);
  const size_t esz = y16 ? 2 : 1;      // y0 element bytes (f16 vs fp8 e4m3)

  char* y0 = (char*)alloc((size_t)Tn * Bn * 2048 * esz);   // ~136MB or ~68MB
  float* hf[5][2];
  f16* hh[5][2];
  for (int d = 0; d < 5; ++d)
    for (int p = 0; p < 2; ++p) {
      hf[d][p] = (float*)alloc((size_t)Bn * Hn * 4);
      hh[d][p] = (f16*)alloc((size_t)Bn * Hn * 2);
    }
  f16* zcat = (f16*)alloc((size_t)Bn * ZDn * 2);
  float* mulv_f = (float*)alloc((size_t)Bn * 512 * 4);
  float* zres_f = (float*)alloc((size_t)Bn * 1120 * 4);
  f16* hidf = (f16*)alloc((size_t)Bn * 4096 * 2);
  f16* xdec = (f16*)alloc((size_t)Bn * 192 * 2);

  // ---- f16 preconverted-weight cascade (graph-safe: ws_size only). ----
  f16 *W16_e1f = nullptr, *W16_e1b = nullptr;
  f16 *W16_e0f = nullptr, *W16_e0b = nullptr;
  f16 *W16_dec = nullptr;
  auto try_allocb = [&](size_t bytes) -> void* {
    size_t o = (off + 255) & ~(size_t)255;
    if (o + bytes > ws_size) return nullptr;
    off = o + bytes;
    return (void*)(wsp + o);
  };
  {
    const size_t e1b = (size_t)3 * Hn * 3072 * 2;   // KWP(2048+1024)=3072
    const size_t e0b = (size_t)3 * Hn * 1152 * 2;   // KWP(96+1024)=1152
    const size_t dcb = (size_t)3 * Hn * 1216 * 2;   // KWP(192+1024)=1216
    size_t save = off;
    f16* a1 = (f16*)try_allocb(e1b); f16* b1 = a1 ? (f16*)try_allocb(e1b) : nullptr;
    if (b1) { W16_e1f = a1; W16_e1b = b1; } else off = save;
    save = off;
    f16* a0 = (f16*)try_allocb(e0b); f16* b0 = a0 ? (f16*)try_allocb(e0b) : nullptr;
    if (b0) { W16_e0f = a0; W16_e0b = b0; } else off = save;
    save = off;
    f16* dc = (f16*)try_allocb(dcb);
    if (dc) W16_dec = dc; else off = save;
  }

  if (W16_e1f) {
    wconvert<<<dim3(3072), dim3(256), 0, stream>>>(
        (const float*)d_in[11], (const float*)d_in[12], 2048, 3072, W16_e1f);
    wconvert<<<dim3(3072), dim3(256), 0, stream>>>(
        (const float*)d_in[15], (const float*)d_in[16], 2048, 3072, W16_e1b);
  }
  if (W16_e0f) {
    wconvert<<<dim3(3072), dim3(256), 0, stream>>>(
        (const float*)d_in[3], (const float*)d_in[4], Cn, 1152, W16_e0f);
    wconvert<<<dim3(3072), dim3(256), 0, stream>>>(
        (const float*)d_in[7], (const float*)d_in[8], Cn, 1152, W16_e0b);
  }
  if (W16_dec)
    wconvert<<<dim3(3072), dim3(256), 0, stream>>>(
        (const float*)d_in[28], (const float*)d_in[29], 192, 1216, W16_dec);

  init_kernel<<<dim3(512), dim3(256), 0, stream>>>(
      hf[0][0], hf[1][0], hf[2][0], hf[3][0],
      hh[0][0], hh[1][0], hh[2][0], hh[3][0],
      xdec, (const float*)d_in[27]);
  melody_fill<<<dim3((MELn / 4 + 255) / 256, Bn), dim3(256), 0, stream>>>(
      (const float*)d_in[1], zcat);

  const int* lenp = (const int*)d_in[34];

  // ---- encoder layer 0 (bidirectional, fused fwd+bwd per launch) ----
  for (int s = 0; s < Tn; ++s) {
    StepArgs a{};
    const int tf = s, tb = Tn - 1 - s;
    const int p = s & 1, q = (s + 1) & 1;
    a.d[0].x = (const float*)d_in[0] + (size_t)tf * Cn;
    a.d[0].Wih = (const float*)d_in[3]; a.d[0].Whh = (const float*)d_in[4];
    a.d[0].bih = (const float*)d_in[5]; a.d[0].bhh = (const float*)d_in[6];
    a.d[0].W16 = W16_e0f;
    a.d[0].hprev_f = hf[0][p]; a.d[0].hprev_h = hh[0][p];
    a.d[0].hcur_f = hf[0][q]; a.d[0].hcur_h = hh[0][q];
    a.d[0].yout = y0 + (size_t)tf * Bn * 2048 * esz;
    a.d[0].t = tf;
    a.d[1].x = (const float*)d_in[0] + (size_t)tb * Cn;
    a.d[1].Wih = (const float*)d_in[7]; a.d[1].Whh = (const float*)d_in[8];
    a.d[1].bih = (const float*)d_in[9]; a.d[1].bhh = (const float*)d_in[10];
    a.d[1].W16 = W16_e0b;
    a.d[1].hprev_f = hf[1][p]; a.d[1].hprev_h = hh[1][p];
    a.d[1].hcur_f = hf[1][q]; a.d[1].hcur_h = hh[1][q];
    a.d[1].yout = y0 + ((size_t)tb * Bn * 2048 + Hn) * esz;
    a.d[1].t = tb;
    a.length = lenp;
    a.xs = Tn * Cn;   // input_x is (B,T,C): batch stride T*C
    if (y16) {
      if (W16_e0f) gru_step_kernel<Cn, 1, 1, 1><<<dim3(32, 4, 2), dim3(512), 0, stream>>>(a);
      else         gru_step_kernel<Cn, 1, 1, 0><<<dim3(32, 4, 2), dim3(256), 0, stream>>>(a);
    } else {
      if (W16_e0f) gru_step_kernel<Cn, 1, 2, 1><<<dim3(32, 4, 2), dim3(512), 0, stream>>>(a);
      else         gru_step_kernel<Cn, 1, 2, 0><<<dim3(32, 4, 2), dim3(256), 0, stream>>>(a);
    }
  }
  // ---- encoder layer 1 ----
  for (int s = 0; s < Tn; ++s) {
    StepArgs a{};
    const int tf = s, tb = Tn - 1 - s;
    const int p = s & 1, q = (s + 1) & 1;
    a.d[0].x = y0 + (size_t)tf * Bn * 2048 * esz;
    a.d[0].Wih = (const float*)d_in[11]; a.d[0].Whh = (const float*)d_in[12];
    a.d[0].bih = (const float*)d_in[13]; a.d[0].bhh = (const float*)d_in[14];
    a.d[0].W16 = W16_e1f;
    a.d[0].hprev_f = hf[2][p]; a.d[0].hprev_h = hh[2][p];
    a.d[0].hcur_f = hf[2][q]; a.d[0].hcur_h = hh[2][q];
    a.d[0].yout = nullptr;
    a.d[0].t = tf;
    a.d[1].x = y0 + (size_t)tb * Bn * 2048 * esz;
    a.d[1].Wih = (const float*)d_in[15]; a.d[1].Whh = (const float*)d_in[16];
    a.d[1].bih = (const float*)d_in[17]; a.d[1].bhh = (const float*)d_in[18];
    a.d[1].W16 = W16_e1b;
    a.d[1].hprev_f = hf[3][p]; a.d[1].hprev_h = hh[3][p];
    a.d[1].hcur_f = hf[3][q]; a.d[1].hcur_h = hh[3][q];
    a.d[1].yout = nullptr;
    a.d[1].t = tb;
    a.length = lenp;
    a.xs = 2048;
    if (y16) {
      if (W16_e1f) gru_step_kernel<2048, 0, 0, 1><<<dim3(32, 4, 2), dim3(512), 0, stream>>>(a);
      else         gru_step_kernel<2048, 0, 0, 0><<<dim3(32, 4, 2), dim3(256), 0, stream>>>(a);
    } else {
      if (W16_e1f) gru_step_kernel<2048, 2, 0, 1><<<dim3(32, 4, 2), dim3(512), 0, stream>>>(a);
      else         gru_step_kernel<2048, 2, 0, 0><<<dim3(32, 4, 2), dim3(256), 0, stream>>>(a);
    }
  }

  // ---- VAE mid-section ----
  build_hid<<<dim3((Bn * Hn + 255) / 256), dim3(256), 0, stream>>>(
      hh[0][0], hh[1][0], hh[2][0], hh[3][0], hidf);
  gemm_nt_kernel<<<dim3(8, 4), dim3(256), 0, stream>>>(
      hidf, (const float*)d_in[19], (const float*)d_in[21],
      (const float*)d_in[20], (const float*)d_in[22], 256, mulv_f, 512, 4096);
  float* outp = (float*)d_out;
  z_kernel<<<dim3((Bn * Ln + 255) / 256), dim3(256), 0, stream>>>(
      mulv_f, (const float*)d_in[2], zcat,
      outp + 2 * (size_t)OUT_SM, outp + 2 * (size_t)OUT_SM + Bn * Ln);
  gemm_nt_kernel<<<dim3(18, 4), dim3(256), 0, stream>>>(
      zcat, (const float*)d_in[23], (const float*)d_in[25],
      (const float*)d_in[24], (const float*)d_in[26], 96, zres_f, 1120, ZDn);
  zscatter<<<dim3((Bn * 1120 + 255) / 256), dim3(256), 0, stream>>>(
      zres_f, xdec, hf[4][0], hh[4][0]);

  // ---- autoregressive decoder ----
  for (int s = 0; s < Tn; ++s) {
    StepArgs a{};
    const int p = s & 1, q = (s + 1) & 1;
    a.d[0].x = xdec;
    a.d[0].Wih = (const float*)d_in[28]; a.d[0].Whh = (const float*)d_in[29];
    a.d[0].bih = (const float*)d_in[30]; a.d[0].bhh = (const float*)d_in[31];
    a.d[0].W16 = W16_dec;
    a.d[0].hprev_f = hf[4][p]; a.d[0].hprev_h = hh[4][p];
    a.d[0].hcur_f = hf[4][q]; a.d[0].hcur_h = hh[4][q];
    a.d[0].yout = nullptr;
    a.d[0].t = s;
    a.d[1] = a.d[0];
    a.length = nullptr;  // decoder: no masking
    a.xs = 192;
    if (W16_dec) gru_step_kernel<192, 0, 0, 1><<<dim3(32, 4, 1), dim3(512), 0, stream>>>(a);
    else         gru_step_kernel<192, 0, 0, 0><<<dim3(32, 4, 1), dim3(256), 0, stream>>>(a);
    outproj_kernel<<<dim3(Bn), dim3(256), 0, stream>>>(
        hf[4][q], (const float*)d_in[32], (const float*)d_in[33],
        outp, xdec, s);
  }

  softmax_kernel<<<dim3((Bn * Tn + 3) / 4), dim3(256), 0, stream>>>(outp);
}